// Round 4
// baseline (504.367 us; speedup 1.0000x reference)
//
#include <hip/hip_runtime.h>
#include <cstdint>
#include <cstddef>

typedef _Float16 half_t;
typedef _Float16 half8 __attribute__((ext_vector_type(8)));
typedef _Float16 half4v __attribute__((ext_vector_type(4)));
typedef float float4_ __attribute__((ext_vector_type(4)));

#define NB 8
#define SEQ 2048
#define DIM 256
#define NROWS (NB*SEQ)   // 16384

// async global->LDS DMA, 16B per lane; LDS dest = wave-uniform base + lane*16
__device__ __forceinline__ void dma16(const half_t* g, half_t* l) {
    __builtin_amdgcn_global_load_lds(
        (const __attribute__((address_space(1))) void*)g,
        (__attribute__((address_space(3))) void*)l,
        16, 0, 0);
}

// ---------------------------------------------------------------------------
// Kernel 1: fold Wc = Wa @ Wk, bc = Wa @ bk + ba; split weights to fp16 hi/lo
// ---------------------------------------------------------------------------
__global__ __launch_bounds__(256) void prep_kernel(
    const float* __restrict__ Wq, const float* __restrict__ Wk,
    const float* __restrict__ Wv, const float* __restrict__ Wa,
    const float* __restrict__ bk, const float* __restrict__ ba,
    half_t* __restrict__ Wq_hi, half_t* __restrict__ Wq_lo,
    half_t* __restrict__ Wc_hi, half_t* __restrict__ Wc_lo,
    half_t* __restrict__ Wv_hi, float* __restrict__ bc)
{
    const int e = blockIdx.x;
    const int d = threadIdx.x;
    const int idx = e * 256 + d;
    float acc = 0.f;
    for (int m = 0; m < 256; ++m)
        acc += Wa[e * 256 + m] * Wk[m * 256 + d];
    half_t h = (half_t)acc;
    Wc_hi[idx] = h;
    Wc_lo[idx] = (half_t)(acc - (float)h);
    float wq = Wq[idx];
    h = (half_t)wq;
    Wq_hi[idx] = h;
    Wq_lo[idx] = (half_t)(wq - (float)h);
    Wv_hi[idx] = (half_t)Wv[idx];
    if (d == 0) {
        float bacc = ba[e];
        for (int m = 0; m < 256; ++m) bacc += Wa[e * 256 + m] * bk[m];
        bc[e] = bacc;
    }
}

// ---------------------------------------------------------------------------
// Kernel 2: linears. seg0: q hi only. seg1: wk hi/lo in attn-tile-swizzled
// global layout. seg2: v -> vT tile-swizzled + key-permuted for reg-P PV.
// ---------------------------------------------------------------------------
__global__ __launch_bounds__(256, 2) void linear_kernel(
    const float* __restrict__ x, const float* __restrict__ states,
    const half_t* __restrict__ Wq_hi, const half_t* __restrict__ Wq_lo, const float* __restrict__ bq,
    const half_t* __restrict__ Wc_hi, const half_t* __restrict__ Wc_lo, const float* __restrict__ bc,
    const half_t* __restrict__ Wv_hi, const float* __restrict__ bv,
    half_t* __restrict__ q_hi,
    half_t* __restrict__ wk_hi, half_t* __restrict__ wk_lo,
    half_t* __restrict__ vT)
{
    __shared__ half_t sB[2 * 64 * 256];   // weights hi+lo = 64 KiB; reused as repack buf
    half_t* sBh = sB;
    half_t* sBl = sB + 64 * 256;

    const int seg  = blockIdx.x >> 8;      // 0:q 1:wk 2:v
    const int t    = blockIdx.x & 255;
    const int tid  = threadIdx.x;
    const int lane = tid & 63;
    const int wv   = tid >> 6;
    const int quad = lane >> 4;
    const int l15  = lane & 15;
    const int rb   = t * 64;               // block row base
    const int r0   = rb + wv * 16;         // wave's 16 rows

    const float* src  = (seg == 0) ? x : states;
    const half_t* Bh  = (seg == 0) ? Wq_hi : (seg == 1) ? Wc_hi : Wv_hi;
    const half_t* Bl  = (seg == 0) ? Wq_lo : Wc_lo;
    const float* bias = (seg == 0) ? bq : (seg == 1) ? bc : bv;

    // A-frags direct from global: A[m=l15 -> row][k=c*32+quad*8+j], hi/lo split
    half8 ah[8], al[8];
    #pragma unroll
    for (int c = 0; c < 8; ++c) {
        const float* pa = src + (size_t)(r0 + l15) * 256 + c * 32 + quad * 8;
        float4_ u0 = *(const float4_*)pa;
        float4_ u1 = *(const float4_*)(pa + 4);
        #pragma unroll
        for (int j = 0; j < 4; ++j) {
            half_t hh = (half_t)u0[j];
            ah[c][j] = hh; al[c][j] = (half_t)(u0[j] - (float)hh);
            hh = (half_t)u1[j];
            ah[c][4 + j] = hh; al[c][4 + j] = (half_t)(u1[j] - (float)hh);
        }
    }

    float4_ acc[16];
    if (seg != 2) {
        #pragma unroll
        for (int nt = 0; nt < 16; ++nt) {
            float be = bias[nt * 16 + l15];
            acc[nt] = {be, be, be, be};
        }
    } else {
        #pragma unroll
        for (int et = 0; et < 16; ++et)
            #pragma unroll
            for (int r = 0; r < 4; ++r)
                acc[et][r] = bias[et * 16 + quad * 4 + r];
    }

    #pragma unroll
    for (int eg = 0; eg < 4; ++eg) {
        __syncthreads();
        // stage weights e-group [64 e][256 k], XOR-swizzled chunks
        #pragma unroll
        for (int i = 0; i < 8; ++i) {
            int g = tid + i * 256;             // 0..2047 chunks
            int e = g >> 5, c = g & 31;
            *(half8*)(sBh + e * 256 + ((c ^ (e & 7)) * 8)) =
                *(const half8*)(Bh + (size_t)(eg * 64 + e) * 256 + c * 8);
        }
        if (seg != 2) {
            #pragma unroll
            for (int i = 0; i < 8; ++i) {
                int g = tid + i * 256;
                int e = g >> 5, c = g & 31;
                *(half8*)(sBl + e * 256 + ((c ^ (e & 7)) * 8)) =
                    *(const half8*)(Bl + (size_t)(eg * 64 + e) * 256 + c * 8);
            }
        }
        __syncthreads();

        if (seg != 2) {
            #pragma unroll
            for (int ntl = 0; ntl < 4; ++ntl) {
                float4_ a = acc[eg * 4 + ntl];
                const int el = ntl * 16 + l15;
                #pragma unroll
                for (int c = 0; c < 8; ++c) {
                    int off = el * 256 + (((c * 4 + quad) ^ (el & 7)) * 8);
                    half8 bh = *(const half8*)(sBh + off);
                    half8 bl = *(const half8*)(sBl + off);
                    a = __builtin_amdgcn_mfma_f32_16x16x32_f16(ah[c], bh, a, 0, 0, 0);
                    a = __builtin_amdgcn_mfma_f32_16x16x32_f16(al[c], bh, a, 0, 0, 0);
                    a = __builtin_amdgcn_mfma_f32_16x16x32_f16(ah[c], bl, a, 0, 0, 0);
                }
                acc[eg * 4 + ntl] = a;
            }
        } else {
            // flipped: A = Wv tile (rows e), B = x rows -> D[e][row]
            #pragma unroll
            for (int ntl = 0; ntl < 4; ++ntl) {
                float4_ a = acc[eg * 4 + ntl];
                const int el = ntl * 16 + l15;
                #pragma unroll
                for (int c = 0; c < 8; ++c) {
                    int off = el * 256 + (((c * 4 + quad) ^ (el & 7)) * 8);
                    half8 aw = *(const half8*)(sBh + off);
                    a = __builtin_amdgcn_mfma_f32_16x16x32_f16(aw, ah[c], a, 0, 0, 0);
                }
                acc[eg * 4 + ntl] = a;
            }
        }
    }

    // epilogue: repack through LDS for coalesced half8 global stores
    __syncthreads();   // weights LDS no longer needed
    if (seg != 2) {
        half_t* R = sB;   // [64 rows][256]
        #pragma unroll
        for (int nt = 0; nt < 16; ++nt)
            #pragma unroll
            for (int r = 0; r < 4; ++r)
                R[(wv * 16 + quad * 4 + r) * 256 + nt * 16 + l15] = (half_t)acc[nt][r];
        __syncthreads();
        if (seg == 0) {
            // q hi only, row-major
            for (int i = 0; i < 8; ++i) {
                int g = tid + i * 256;                 // 2048 chunks
                int row = g >> 5, cc = g & 31;
                *(half8*)(q_hi + (size_t)(rb + row) * 256 + cc * 8) =
                    *(const half8*)(R + row * 256 + cc * 8);
            }
        } else {
            // wk hi: tile-swizzled layout (tile=32 keys, 8192 elems)
            for (int i = 0; i < 8; ++i) {
                int g = tid + i * 256;
                int row = g >> 5, cc = g & 31;
                int s = row & 31;
                size_t dst = ((size_t)(rb + row) >> 5) * 8192 + s * 256 + ((cc ^ (s & 7)) * 8);
                *(half8*)(wk_hi + dst) = *(const half8*)(R + row * 256 + cc * 8);
            }
            __syncthreads();
            #pragma unroll
            for (int nt = 0; nt < 16; ++nt)
                #pragma unroll
                for (int r = 0; r < 4; ++r) {
                    float v = acc[nt][r];
                    half_t hh = (half_t)v;
                    R[(wv * 16 + quad * 4 + r) * 256 + nt * 16 + l15] = (half_t)(v - (float)hh);
                }
            __syncthreads();
            for (int i = 0; i < 8; ++i) {
                int g = tid + i * 256;
                int row = g >> 5, cc = g & 31;
                int s = row & 31;
                size_t dst = ((size_t)(rb + row) >> 5) * 8192 + s * 256 + ((cc ^ (s & 7)) * 8);
                *(half8*)(wk_lo + dst) = *(const half8*)(R + row * 256 + cc * 8);
            }
        }
    } else {
        // vT repack: sV [d 256][s 64] stride 68, then tile-swizzled stores.
        // Key permutation: logical chunk q of a 32-key tile holds keys
        // {t32+4q+j}(j<4) and {t32+16+4q+(j-4)}(j>=4) -- matches the natural
        // per-lane P ownership of the attn QK^T output.
        half_t* sV = sB;
        #pragma unroll
        for (int et = 0; et < 16; ++et)
            #pragma unroll
            for (int r = 0; r < 4; ++r)
                sV[(et * 16 + quad * 4 + r) * 68 + wv * 16 + l15] = (half_t)acc[et][r];
        __syncthreads();
        const int b = rb >> 11, s0 = rb & 2047;
        for (int i = 0; i < 8; ++i) {
            int g = tid + i * 256;                 // 2048 chunks: d 256 x sc8 8
            int d = g >> 3, sc8 = g & 7;
            int kt = (s0 >> 5) + (sc8 >> 2);
            int q  = sc8 & 3;                      // logical key-chunk
            int t32 = (sc8 >> 2) * 32;
            int slot = q ^ (d & 3) ^ ((d >> 2) & 3);
            half4v a4 = *(const half4v*)(sV + d * 68 + t32 + q * 4);
            half4v b4 = *(const half4v*)(sV + d * 68 + t32 + 16 + q * 4);
            half8 hv;
            hv[0] = a4[0]; hv[1] = a4[1]; hv[2] = a4[2]; hv[3] = a4[3];
            hv[4] = b4[0]; hv[5] = b4[1]; hv[6] = b4[2]; hv[7] = b4[3];
            size_t dst = ((size_t)b * 64 + kt) * 8192 + d * 32 + slot * 8;
            *(half8*)(vT + dst) = hv;
        }
    }
}

// ---------------------------------------------------------------------------
// Kernel 3: flash attention, 8-wave blocks (256 q-rows), 48 KiB LDS (wk hi/lo
// + vt, all single-buffered) -> 2 blocks/CU = 16 waves/CU (4/SIMD), double
// the previous occupancy; one tile-stage now feeds 8 waves (staging halved).
// 4 raw barriers/iter, counted vmcnt, every wait covered by a full phase:
//   A: wait wk(it)   [issued after B(it-1), cover = softmax+PV]
//   B: QK done -> issue wk(it+1)
//   C: wait vt(it)   [issued after D(it-1), cover = QK+softmax]
//   D: PV done -> issue vt(it+1)
// Per-wave staging: wk 4 ops, vt 2 ops -> steady-state waits vmcnt(2)/vmcnt(4).
// ---------------------------------------------------------------------------
template<int KSV>
__global__ __launch_bounds__(512, 4) void attn_kernel(
    const half_t* __restrict__ q_hi,
    const half_t* __restrict__ wk_hi, const half_t* __restrict__ wk_lo,
    const half_t* __restrict__ vT,
    half_t* __restrict__ pc, float* __restrict__ pm, float* __restrict__ pl)
{
    constexpr int NITV = 64 / KSV;               // key-tiles per block
    __shared__ __align__(16) unsigned char smem[48 * 1024];
    half_t* s_wk_hi = (half_t*)smem;             // [32 key][256 k] swizzled image
    half_t* s_wk_lo = (half_t*)(smem + 16384);
    half_t* s_vt    = (half_t*)(smem + 32768);   // [256 d][32 key] swizzled image
    float*  scr     = (float*)smem;              // epilogue overlay (2-phase)

    const int tid  = threadIdx.x;
    const int lane = tid & 63;
    const int wv   = tid >> 6;                   // 0..7
    const int quad = lane >> 4;
    const int l15  = lane & 15;

    const int b  = blockIdx.x & 7;               // XCD-swizzle: batch per XCD
    const int qt = (blockIdx.x >> 3) & 7;        // q-tile 0..7 (256 rows each)
    const int ks = blockIdx.x >> 6;              // k-split 0..KSV-1

    const int qbase = b * 2048 + qt * 256 + wv * 32;   // wave's 32 q-rows

    // q B-frags resident (hi plane only): B[n=qcol][k=c*32+quad*8+j]
    half8 qf[2][8];
    #pragma unroll
    for (int ct = 0; ct < 2; ++ct)
        #pragma unroll
        for (int c = 0; c < 8; ++c)
            qf[ct][c] = *(const half8*)(q_hi +
                (size_t)(qbase + ct * 16 + l15) * 256 + c * 32 + quad * 8);

    float4_ ctx[16][2];
    #pragma unroll
    for (int dt = 0; dt < 16; ++dt) {
        ctx[dt][0] = {0.f, 0.f, 0.f, 0.f};
        ctx[dt][1] = {0.f, 0.f, 0.f, 0.f};
    }
    float m_c[2] = {-1e30f, -1e30f};
    float l_c[2] = {0.f, 0.f};

    const half_t* wkh_b = wk_hi + (size_t)b * 64 * 8192;  // tiled layout
    const half_t* wkl_b = wk_lo + (size_t)b * 64 * 8192;
    const half_t* vt_b  = vT    + (size_t)b * 64 * 8192;
    const int t0 = ks * NITV;

    // prologue: wave wv stages segments {wv, wv+8} of each 16 KiB plane
    {
        const half_t* wh_t = wkh_b + (size_t)t0 * 8192;
        const half_t* wl_t = wkl_b + (size_t)t0 * 8192;
        const half_t* vt_t = vt_b  + (size_t)t0 * 8192;
        dma16(wh_t + wv * 512 + lane * 8,       s_wk_hi + wv * 512);
        dma16(wh_t + (wv + 8) * 512 + lane * 8, s_wk_hi + (wv + 8) * 512);
        dma16(wl_t + wv * 512 + lane * 8,       s_wk_lo + wv * 512);
        dma16(wl_t + (wv + 8) * 512 + lane * 8, s_wk_lo + (wv + 8) * 512);
        dma16(vt_t + wv * 512 + lane * 8,       s_vt + wv * 512);
        dma16(vt_t + (wv + 8) * 512 + lane * 8, s_vt + (wv + 8) * 512);
    }

    for (int it = 0; it < NITV; ++it) {
        const bool pre = (it + 1 < NITV);

        // in flight at top: wk(it) 4 + vt(it) 2 (per wave)
        asm volatile("s_waitcnt vmcnt(2)" ::: "memory");   // drain wk(it)
        __builtin_amdgcn_s_barrier();        // (A) wk(it) resident
        asm volatile("" ::: "memory");

        // ---- S^T = wk . q^T : tiles [kt 16-keys][ct 16-qcols], hi/lo on wk
        float4_ S[2][2];
        S[0][0] = {0.f,0.f,0.f,0.f}; S[0][1] = {0.f,0.f,0.f,0.f};
        S[1][0] = {0.f,0.f,0.f,0.f}; S[1][1] = {0.f,0.f,0.f,0.f};
        __builtin_amdgcn_s_setprio(1);
        #pragma unroll
        for (int c = 0; c < 8; ++c)
            #pragma unroll
            for (int kt = 0; kt < 2; ++kt) {
                const int key = kt * 16 + l15;
                const int off = key * 256 + (((c * 4 + quad) ^ (key & 7)) * 8);
                half8 wh = *(const half8*)(s_wk_hi + off);
                half8 wl = *(const half8*)(s_wk_lo + off);
                #pragma unroll
                for (int ct = 0; ct < 2; ++ct) {
                    S[kt][ct] = __builtin_amdgcn_mfma_f32_16x16x32_f16(wh, qf[ct][c], S[kt][ct], 0, 0, 0);
                    S[kt][ct] = __builtin_amdgcn_mfma_f32_16x16x32_f16(wl, qf[ct][c], S[kt][ct], 0, 0, 0);
                }
            }
        __builtin_amdgcn_s_setprio(0);
        __builtin_amdgcn_sched_barrier(0);   // pin QK cluster + its lgkm waits
        __builtin_amdgcn_s_barrier();        // (B) QK done -> wk bufs free
        asm volatile("" ::: "memory");

        if (pre) {
            const int ktn = t0 + it + 1;
            const half_t* wh_t = wkh_b + (size_t)ktn * 8192;
            const half_t* wl_t = wkl_b + (size_t)ktn * 8192;
            dma16(wh_t + wv * 512 + lane * 8,       s_wk_hi + wv * 512);
            dma16(wh_t + (wv + 8) * 512 + lane * 8, s_wk_hi + (wv + 8) * 512);
            dma16(wl_t + wv * 512 + lane * 8,       s_wk_lo + wv * 512);
            dma16(wl_t + (wv + 8) * 512 + lane * 8, s_wk_lo + (wv + 8) * 512);
        }

        // ---- softmax (VALU, overlaps DMA flight); lane owns qcol ct*16+l15
        float mx0, mx1;
        {
            float a0 = fmaxf(fmaxf(S[0][0][0], S[0][0][1]), fmaxf(S[0][0][2], S[0][0][3]));
            float b0 = fmaxf(fmaxf(S[1][0][0], S[1][0][1]), fmaxf(S[1][0][2], S[1][0][3]));
            mx0 = fmaxf(a0, b0);
            mx0 = fmaxf(mx0, __shfl_xor(mx0, 16));
            mx0 = fmaxf(mx0, __shfl_xor(mx0, 32));
            float a1 = fmaxf(fmaxf(S[0][1][0], S[0][1][1]), fmaxf(S[0][1][2], S[0][1][3]));
            float b1 = fmaxf(fmaxf(S[1][1][0], S[1][1][1]), fmaxf(S[1][1][2], S[1][1][3]));
            mx1 = fmaxf(a1, b1);
            mx1 = fmaxf(mx1, __shfl_xor(mx1, 16));
            mx1 = fmaxf(mx1, __shfl_xor(mx1, 32));
        }
        // defer-rescale: keep frozen max while tile max within THR=8
        const int doresc = __any((mx0 > m_c[0] + 8.f) || (mx1 > m_c[1] + 8.f));
        float alpha0 = 1.f, alpha1 = 1.f;
        if (doresc) {
            float mn0 = fmaxf(m_c[0], mx0);
            float mn1 = fmaxf(m_c[1], mx1);
            alpha0 = __expf(m_c[0] - mn0);
            alpha1 = __expf(m_c[1] - mn1);
            m_c[0] = mn0; m_c[1] = mn1;
        }
        // P stays in registers: pf[ct] is directly the PV B-frag (producer-side
        // key permutation of vT).
        half8 pf[2];
        #pragma unroll
        for (int ct = 0; ct < 2; ++ct) {
            const float mm = m_c[ct];
            float rs = 0.f;
            #pragma unroll
            for (int r = 0; r < 4; ++r) {
                float p0 = __expf(S[0][ct][r] - mm);
                float p1 = __expf(S[1][ct][r] - mm);
                rs += p0 + p1;
                pf[ct][r]     = (half_t)p0;
                pf[ct][4 + r] = (half_t)p1;
            }
            rs += __shfl_xor(rs, 16);
            rs += __shfl_xor(rs, 32);
            l_c[ct] = l_c[ct] * (ct ? alpha1 : alpha0) + rs;
        }
        if (doresc) {
            #pragma unroll
            for (int dt = 0; dt < 16; ++dt)
                #pragma unroll
                for (int r = 0; r < 4; ++r) {
                    ctx[dt][0][r] *= alpha0;
                    ctx[dt][1][r] *= alpha1;
                }
        }

        // drain vt(it); keep wk(it+1) (4 ops) in flight
        if (pre) asm volatile("s_waitcnt vmcnt(4)" ::: "memory");
        else     asm volatile("s_waitcnt vmcnt(0)" ::: "memory");
        __builtin_amdgcn_s_barrier();        // (C) vt(it) resident
        asm volatile("" ::: "memory");

        // ---- ctx^T += vT_tile . P^T
        __builtin_amdgcn_s_setprio(1);
        #pragma unroll
        for (int dt = 0; dt < 16; ++dt) {
            const int d = dt * 16 + l15;
            half8 vf = *(const half8*)(s_vt + d * 32 + ((quad ^ (d & 3) ^ ((d >> 2) & 3)) * 8));
            ctx[dt][0] = __builtin_amdgcn_mfma_f32_16x16x32_f16(vf, pf[0], ctx[dt][0], 0, 0, 0);
            ctx[dt][1] = __builtin_amdgcn_mfma_f32_16x16x32_f16(vf, pf[1], ctx[dt][1], 0, 0, 0);
        }
        __builtin_amdgcn_s_setprio(0);
        __builtin_amdgcn_sched_barrier(0);   // pin PV cluster + its lgkm waits
        __builtin_amdgcn_s_barrier();        // (D) PV done -> vt buf free
        asm volatile("" ::: "memory");

        if (pre) {
            const half_t* vt_t = vt_b + (size_t)(t0 + it + 1) * 8192;
            dma16(vt_t + wv * 512 + lane * 8,       s_vt + wv * 512);
            dma16(vt_t + (wv + 8) * 512 + lane * 8, s_vt + (wv + 8) * 512);
        }
    }

    // epilogue: normalized partial context (fp16) via per-wave LDS transpose.
    // Final C drained all DMA (vmcnt(0)); final D certified all waves past PV.
    // 8 waves need 2 phases of the 34.8 KiB f32 scratch (4 regions).
    float rinv[2] = {1.0f / l_c[0], 1.0f / l_c[1]};
    half_t* pcs = pc + (size_t)ks * NROWS * 256;
    #pragma unroll
    for (int ph = 0; ph < 2; ++ph) {
        if ((wv >> 2) == ph) {
            float* sw = scr + (wv & 3) * (32 * 68);   // [q 32][stride 68] f32
            #pragma unroll
            for (int rd = 0; rd < 4; ++rd) {
                #pragma unroll
                for (int dtl = 0; dtl < 4; ++dtl) {
                    const int dt = rd * 4 + dtl;
                    #pragma unroll
                    for (int ct = 0; ct < 2; ++ct)
                        #pragma unroll
                        for (int r = 0; r < 4; ++r)
                            sw[(ct * 16 + l15) * 68 + dtl * 16 + quad * 4 + r] = ctx[dt][ct][r] * rinv[ct];
                }
                #pragma unroll
                for (int i = 0; i < 8; ++i) {
                    int g = lane + i * 64;
                    int q = g >> 4, dc = g & 15;
                    float4_ v4 = *(const float4_*)(sw + q * 68 + dc * 4);
                    half4v h4;
                    #pragma unroll
                    for (int j = 0; j < 4; ++j) h4[j] = (half_t)v4[j];
                    *(half4v*)(pcs + (size_t)(qbase + q) * 256 + rd * 64 + dc * 4) = h4;
                }
            }
        }
        __syncthreads();
    }
    if (quad == 0) {
        #pragma unroll
        for (int ct = 0; ct < 2; ++ct) {
            const size_t row = qbase + ct * 16 + l15;
            pm[(size_t)ks * NROWS + row] = m_c[ct];
            pl[(size_t)ks * NROWS + row] = l_c[ct];
        }
    }
}

// ---------------------------------------------------------------------------
// Kernel 4: merge the KSV k-split partials.
// ---------------------------------------------------------------------------
template<int KSV>
__global__ __launch_bounds__(256) void combine_kernel(
    const half_t* __restrict__ pc, const float* __restrict__ pm,
    const float* __restrict__ pl, float* __restrict__ out)
{
    const int t = threadIdx.x;
    const int row = blockIdx.x * 4 + (t >> 6);
    const int d0 = (t & 63) * 4;
    float m[KSV], l[KSV];
    float ms = -1e30f;
    #pragma unroll
    for (int i = 0; i < KSV; ++i) {
        m[i] = pm[(size_t)i * NROWS + row];
        l[i] = pl[(size_t)i * NROWS + row];
        ms = fmaxf(ms, m[i]);
    }
    float w[KSV], tot = 0.f;
    #pragma unroll
    for (int i = 0; i < KSV; ++i) {
        w[i] = l[i] * __expf(m[i] - ms);
        tot += w[i];
    }
    float inv = 1.0f / tot;
    float4_ o = {0.f, 0.f, 0.f, 0.f};
    #pragma unroll
    for (int i = 0; i < KSV; ++i) {
        half4v y = *(const half4v*)(pc + ((size_t)i * NROWS + row) * 256 + d0);
        float wi = w[i] * inv;
        #pragma unroll
        for (int j = 0; j < 4; ++j) o[j] += wi * (float)y[j];
    }
    *(float4_*)(out + (size_t)row * 256 + d0) = o;
}

// ---------------------------------------------------------------------------
extern "C" void kernel_launch(void* const* d_in, const int* in_sizes, int n_in,
                              void* d_out, int out_size, void* d_ws, size_t ws_size,
                              hipStream_t stream) {
    const float* x      = (const float*)d_in[0];
    const float* states = (const float*)d_in[1];
    const float* Wq     = (const float*)d_in[2];
    const float* bq     = (const float*)d_in[3];
    const float* Wk     = (const float*)d_in[4];
    const float* bk     = (const float*)d_in[5];
    const float* Wv     = (const float*)d_in[6];
    const float* bv     = (const float*)d_in[7];
    const float* Wa     = (const float*)d_in[8];
    const float* ba     = (const float*)d_in[9];
    float* out = (float*)d_out;

    // workspace requirement for a given k-split
    auto need = [](int ksv) -> size_t {
        size_t o = 0;
        auto a = [&](size_t bb) { o += (bb + 255) & ~(size_t)255; };
        for (int i = 0; i < 5; ++i) a(65536 * 2);     // weight planes
        a(256 * 4);                                   // bc
        for (int i = 0; i < 4; ++i) a((size_t)NROWS * 256 * 2);  // q,wkh,wkl,vT
        a((size_t)ksv * NROWS * 256 * 2);             // pc
        a((size_t)ksv * NROWS * 4);                   // pm
        a((size_t)ksv * NROWS * 4);                   // pl
        return o;
    };
    const int KSV = (ws_size >= need(8)) ? 8 : 4;

    char* ws = (char*)d_ws;
    size_t off = 0;
    auto alloc = [&](size_t bytes) -> void* {
        void* p = ws + off;
        off += (bytes + 255) & ~(size_t)255;
        return p;
    };
    half_t* Wq_hi = (half_t*)alloc(65536 * 2);
    half_t* Wq_lo = (half_t*)alloc(65536 * 2);
    half_t* Wc_hi = (half_t*)alloc(65536 * 2);
    half_t* Wc_lo = (half_t*)alloc(65536 * 2);
    half_t* Wv_hi = (half_t*)alloc(65536 * 2);
    float*  bc    = (float*)alloc(256 * 4);
    half_t* q_hi  = (half_t*)alloc((size_t)NROWS * 256 * 2);
    half_t* wk_hi = (half_t*)alloc((size_t)NROWS * 256 * 2);   // tiled layout
    half_t* wk_lo = (half_t*)alloc((size_t)NROWS * 256 * 2);   // tiled layout
    half_t* vT    = (half_t*)alloc((size_t)NROWS * 256 * 2);   // tiled layout
    half_t* pc    = (half_t*)alloc((size_t)KSV * NROWS * 256 * 2);
    float*  pm    = (float*)alloc((size_t)KSV * NROWS * 4);
    float*  pl    = (float*)alloc((size_t)KSV * NROWS * 4);

    prep_kernel<<<256, 256, 0, stream>>>(Wq, Wk, Wv, Wa, bk, ba,
                                         Wq_hi, Wq_lo, Wc_hi, Wc_lo, Wv_hi, bc);
    linear_kernel<<<768, 256, 0, stream>>>(x, states,
                                           Wq_hi, Wq_lo, bq,
                                           Wc_hi, Wc_lo, bc,
                                           Wv_hi, bv,
                                           q_hi, wk_hi, wk_lo, vT);
    if (KSV == 8) {
        attn_kernel<8><<<NB * 8 * 8, 512, 0, stream>>>(q_hi, wk_hi, wk_lo, vT,
                                                       pc, pm, pl);
        combine_kernel<8><<<NROWS / 4, 256, 0, stream>>>(pc, pm, pl, out);
    } else {
        attn_kernel<4><<<NB * 8 * 4, 512, 0, stream>>>(q_hi, wk_hi, wk_lo, vT,
                                                       pc, pm, pl);
        combine_kernel<4><<<NROWS / 4, 256, 0, stream>>>(pc, pm, pl, out);
    }
}

// Round 5
// 264.360 us; speedup vs baseline: 1.9079x; 1.9079x over previous
//
#include <hip/hip_runtime.h>
#include <cstdint>
#include <cstddef>

typedef _Float16 half_t;
typedef _Float16 half8 __attribute__((ext_vector_type(8)));
typedef _Float16 half4v __attribute__((ext_vector_type(4)));
typedef float float4_ __attribute__((ext_vector_type(4)));

#define NB 8
#define SEQ 2048
#define DIM 256
#define NROWS (NB*SEQ)   // 16384
#define KS 4             // k-split -> grid 512 = 2 blocks/CU
#define NIT 16           // (2048/KS)/32 key-tiles per block

// async global->LDS DMA, 16B per lane; LDS dest = wave-uniform base + lane*16
__device__ __forceinline__ void dma16(const half_t* g, half_t* l) {
    __builtin_amdgcn_global_load_lds(
        (const __attribute__((address_space(1))) void*)g,
        (__attribute__((address_space(3))) void*)l,
        16, 0, 0);
}

// ---------------------------------------------------------------------------
// Kernel 1: fold Wc = Wa @ Wk, bc = Wa @ bk + ba; split weights to fp16 hi/lo
// ---------------------------------------------------------------------------
__global__ __launch_bounds__(256) void prep_kernel(
    const float* __restrict__ Wq, const float* __restrict__ Wk,
    const float* __restrict__ Wv, const float* __restrict__ Wa,
    const float* __restrict__ bk, const float* __restrict__ ba,
    half_t* __restrict__ Wq_hi, half_t* __restrict__ Wq_lo,
    half_t* __restrict__ Wc_hi, half_t* __restrict__ Wc_lo,
    half_t* __restrict__ Wv_hi, float* __restrict__ bc)
{
    const int e = blockIdx.x;
    const int d = threadIdx.x;
    const int idx = e * 256 + d;
    float acc = 0.f;
    for (int m = 0; m < 256; ++m)
        acc += Wa[e * 256 + m] * Wk[m * 256 + d];
    half_t h = (half_t)acc;
    Wc_hi[idx] = h;
    Wc_lo[idx] = (half_t)(acc - (float)h);
    float wq = Wq[idx];
    h = (half_t)wq;
    Wq_hi[idx] = h;
    Wq_lo[idx] = (half_t)(wq - (float)h);
    Wv_hi[idx] = (half_t)Wv[idx];
    if (d == 0) {
        float bacc = ba[e];
        for (int m = 0; m < 256; ++m) bacc += Wa[e * 256 + m] * bk[m];
        bc[e] = bacc;
    }
}

// ---------------------------------------------------------------------------
// Kernel 2: linears. seg0: q hi only. seg1: wk hi/lo in attn-tile-swizzled
// global layout. seg2: v -> vT tile-swizzled + key-permuted for reg-P PV.
// ---------------------------------------------------------------------------
__global__ __launch_bounds__(256, 2) void linear_kernel(
    const float* __restrict__ x, const float* __restrict__ states,
    const half_t* __restrict__ Wq_hi, const half_t* __restrict__ Wq_lo, const float* __restrict__ bq,
    const half_t* __restrict__ Wc_hi, const half_t* __restrict__ Wc_lo, const float* __restrict__ bc,
    const half_t* __restrict__ Wv_hi, const float* __restrict__ bv,
    half_t* __restrict__ q_hi,
    half_t* __restrict__ wk_hi, half_t* __restrict__ wk_lo,
    half_t* __restrict__ vT)
{
    __shared__ half_t sB[2 * 64 * 256];   // weights hi+lo = 64 KiB; reused as repack buf
    half_t* sBh = sB;
    half_t* sBl = sB + 64 * 256;

    const int seg  = blockIdx.x >> 8;      // 0:q 1:wk 2:v
    const int t    = blockIdx.x & 255;
    const int tid  = threadIdx.x;
    const int lane = tid & 63;
    const int wv   = tid >> 6;
    const int quad = lane >> 4;
    const int l15  = lane & 15;
    const int rb   = t * 64;               // block row base
    const int r0   = rb + wv * 16;         // wave's 16 rows

    const float* src  = (seg == 0) ? x : states;
    const half_t* Bh  = (seg == 0) ? Wq_hi : (seg == 1) ? Wc_hi : Wv_hi;
    const half_t* Bl  = (seg == 0) ? Wq_lo : Wc_lo;
    const float* bias = (seg == 0) ? bq : (seg == 1) ? bc : bv;

    // A-frags direct from global: A[m=l15 -> row][k=c*32+quad*8+j], hi/lo split
    half8 ah[8], al[8];
    #pragma unroll
    for (int c = 0; c < 8; ++c) {
        const float* pa = src + (size_t)(r0 + l15) * 256 + c * 32 + quad * 8;
        float4_ u0 = *(const float4_*)pa;
        float4_ u1 = *(const float4_*)(pa + 4);
        #pragma unroll
        for (int j = 0; j < 4; ++j) {
            half_t hh = (half_t)u0[j];
            ah[c][j] = hh; al[c][j] = (half_t)(u0[j] - (float)hh);
            hh = (half_t)u1[j];
            ah[c][4 + j] = hh; al[c][4 + j] = (half_t)(u1[j] - (float)hh);
        }
    }

    float4_ acc[16];
    if (seg != 2) {
        #pragma unroll
        for (int nt = 0; nt < 16; ++nt) {
            float be = bias[nt * 16 + l15];
            acc[nt] = {be, be, be, be};
        }
    } else {
        #pragma unroll
        for (int et = 0; et < 16; ++et)
            #pragma unroll
            for (int r = 0; r < 4; ++r)
                acc[et][r] = bias[et * 16 + quad * 4 + r];
    }

    #pragma unroll
    for (int eg = 0; eg < 4; ++eg) {
        __syncthreads();
        // stage weights e-group [64 e][256 k], XOR-swizzled chunks
        #pragma unroll
        for (int i = 0; i < 8; ++i) {
            int g = tid + i * 256;             // 0..2047 chunks
            int e = g >> 5, c = g & 31;
            *(half8*)(sBh + e * 256 + ((c ^ (e & 7)) * 8)) =
                *(const half8*)(Bh + (size_t)(eg * 64 + e) * 256 + c * 8);
        }
        if (seg != 2) {
            #pragma unroll
            for (int i = 0; i < 8; ++i) {
                int g = tid + i * 256;
                int e = g >> 5, c = g & 31;
                *(half8*)(sBl + e * 256 + ((c ^ (e & 7)) * 8)) =
                    *(const half8*)(Bl + (size_t)(eg * 64 + e) * 256 + c * 8);
            }
        }
        __syncthreads();

        if (seg != 2) {
            #pragma unroll
            for (int ntl = 0; ntl < 4; ++ntl) {
                float4_ a = acc[eg * 4 + ntl];
                const int el = ntl * 16 + l15;
                #pragma unroll
                for (int c = 0; c < 8; ++c) {
                    int off = el * 256 + (((c * 4 + quad) ^ (el & 7)) * 8);
                    half8 bh = *(const half8*)(sBh + off);
                    half8 bl = *(const half8*)(sBl + off);
                    a = __builtin_amdgcn_mfma_f32_16x16x32_f16(ah[c], bh, a, 0, 0, 0);
                    a = __builtin_amdgcn_mfma_f32_16x16x32_f16(al[c], bh, a, 0, 0, 0);
                    a = __builtin_amdgcn_mfma_f32_16x16x32_f16(ah[c], bl, a, 0, 0, 0);
                }
                acc[eg * 4 + ntl] = a;
            }
        } else {
            // flipped: A = Wv tile (rows e), B = x rows -> D[e][row]
            #pragma unroll
            for (int ntl = 0; ntl < 4; ++ntl) {
                float4_ a = acc[eg * 4 + ntl];
                const int el = ntl * 16 + l15;
                #pragma unroll
                for (int c = 0; c < 8; ++c) {
                    int off = el * 256 + (((c * 4 + quad) ^ (el & 7)) * 8);
                    half8 aw = *(const half8*)(sBh + off);
                    a = __builtin_amdgcn_mfma_f32_16x16x32_f16(aw, ah[c], a, 0, 0, 0);
                }
                acc[eg * 4 + ntl] = a;
            }
        }
    }

    // epilogue: repack through LDS for coalesced half8 global stores
    __syncthreads();   // weights LDS no longer needed
    if (seg != 2) {
        half_t* R = sB;   // [64 rows][256]
        #pragma unroll
        for (int nt = 0; nt < 16; ++nt)
            #pragma unroll
            for (int r = 0; r < 4; ++r)
                R[(wv * 16 + quad * 4 + r) * 256 + nt * 16 + l15] = (half_t)acc[nt][r];
        __syncthreads();
        if (seg == 0) {
            // q hi only, row-major
            for (int i = 0; i < 8; ++i) {
                int g = tid + i * 256;                 // 2048 chunks
                int row = g >> 5, cc = g & 31;
                *(half8*)(q_hi + (size_t)(rb + row) * 256 + cc * 8) =
                    *(const half8*)(R + row * 256 + cc * 8);
            }
        } else {
            // wk hi: tile-swizzled layout (tile=32 keys, 8192 elems)
            for (int i = 0; i < 8; ++i) {
                int g = tid + i * 256;
                int row = g >> 5, cc = g & 31;
                int s = row & 31;
                size_t dst = ((size_t)(rb + row) >> 5) * 8192 + s * 256 + ((cc ^ (s & 7)) * 8);
                *(half8*)(wk_hi + dst) = *(const half8*)(R + row * 256 + cc * 8);
            }
            __syncthreads();
            #pragma unroll
            for (int nt = 0; nt < 16; ++nt)
                #pragma unroll
                for (int r = 0; r < 4; ++r) {
                    float v = acc[nt][r];
                    half_t hh = (half_t)v;
                    R[(wv * 16 + quad * 4 + r) * 256 + nt * 16 + l15] = (half_t)(v - (float)hh);
                }
            __syncthreads();
            for (int i = 0; i < 8; ++i) {
                int g = tid + i * 256;
                int row = g >> 5, cc = g & 31;
                int s = row & 31;
                size_t dst = ((size_t)(rb + row) >> 5) * 8192 + s * 256 + ((cc ^ (s & 7)) * 8);
                *(half8*)(wk_lo + dst) = *(const half8*)(R + row * 256 + cc * 8);
            }
        }
    } else {
        // vT repack: sV [d 256][s 64] stride 68, then tile-swizzled stores.
        // Key permutation: logical chunk q of a 32-key tile holds keys
        // {t32+4q+j}(j<4) and {t32+16+4q+(j-4)}(j>=4) -- matches the natural
        // per-lane P ownership of the attn QK^T output.
        half_t* sV = sB;
        #pragma unroll
        for (int et = 0; et < 16; ++et)
            #pragma unroll
            for (int r = 0; r < 4; ++r)
                sV[(et * 16 + quad * 4 + r) * 68 + wv * 16 + l15] = (half_t)acc[et][r];
        __syncthreads();
        const int b = rb >> 11, s0 = rb & 2047;
        for (int i = 0; i < 8; ++i) {
            int g = tid + i * 256;                 // 2048 chunks: d 256 x sc8 8
            int d = g >> 3, sc8 = g & 7;
            int kt = (s0 >> 5) + (sc8 >> 2);
            int q  = sc8 & 3;                      // logical key-chunk
            int t32 = (sc8 >> 2) * 32;
            int slot = q ^ (d & 3) ^ ((d >> 2) & 3);
            half4v a4 = *(const half4v*)(sV + d * 68 + t32 + q * 4);
            half4v b4 = *(const half4v*)(sV + d * 68 + t32 + 16 + q * 4);
            half8 hv;
            hv[0] = a4[0]; hv[1] = a4[1]; hv[2] = a4[2]; hv[3] = a4[3];
            hv[4] = b4[0]; hv[5] = b4[1]; hv[6] = b4[2]; hv[7] = b4[3];
            size_t dst = ((size_t)b * 64 + kt) * 8192 + d * 32 + slot * 8;
            *(half8*)(vT + dst) = hv;
        }
    }
}

// ---------------------------------------------------------------------------
// Kernel 3: flash attention, vt DIRECT-FROM-L2 (no vt staging, no C/D
// barriers). wk hi/lo LDS-staged (32 KiB), 2 barriers/iter:
//   A: wait wk(it) [vmcnt(0): only wk in flight at top] -> QK
//   B: QK done -> issue wk(it+1) DMA; vt reg-loads (2x8 chunks) stream from
//      L2 under softmax/PV; compiler pipelines the vmcnt waits.
// vt tile (16 KiB) is L2-resident (3 MB/batch, XCD-pinned by b-swizzle);
// each wave reads a contiguous permuted 1 KiB block per dt -- coalesced.
// Per-wave regs: ctx 128 + qf 32 + vf 64 transient + misc ~= 248 < 256 cap.
// ---------------------------------------------------------------------------
__global__ __launch_bounds__(256, 2) void attn_kernel(
    const half_t* __restrict__ q_hi,
    const half_t* __restrict__ wk_hi, const half_t* __restrict__ wk_lo,
    const half_t* __restrict__ vT,
    half_t* __restrict__ pc, float* __restrict__ pm, float* __restrict__ pl)
{
    __shared__ __align__(16) unsigned char smem[36 * 1024];
    half_t* s_wk_hi = (half_t*)smem;             // [32 key][256 k] swizzled image
    half_t* s_wk_lo = (half_t*)(smem + 16384);
    float*  scr     = (float*)smem;              // epilogue overlay (34.8 KiB)

    const int tid  = threadIdx.x;
    const int lane = tid & 63;
    const int wv   = tid >> 6;
    const int quad = lane >> 4;
    const int l15  = lane & 15;

    const int b  = blockIdx.x & 7;          // XCD-swizzle: batch per XCD
    const int qt = (blockIdx.x >> 3) & 15;  // q-tile 0..15 (128 rows each)
    const int ks = blockIdx.x >> 7;         // k-split quarter 0..3

    const int qbase = b * 2048 + qt * 128 + wv * 32;   // wave's 32 q-rows

    // q B-frags resident (hi plane only): B[n=qcol][k=c*32+quad*8+j]
    half8 qf[2][8];
    #pragma unroll
    for (int ct = 0; ct < 2; ++ct)
        #pragma unroll
        for (int c = 0; c < 8; ++c)
            qf[ct][c] = *(const half8*)(q_hi +
                (size_t)(qbase + ct * 16 + l15) * 256 + c * 32 + quad * 8);

    float4_ ctx[16][2];
    #pragma unroll
    for (int dt = 0; dt < 16; ++dt) {
        ctx[dt][0] = {0.f, 0.f, 0.f, 0.f};
        ctx[dt][1] = {0.f, 0.f, 0.f, 0.f};
    }
    float m_c[2] = {-1e30f, -1e30f};
    float l_c[2] = {0.f, 0.f};

    const half_t* wkh_b = wk_hi + (size_t)b * 64 * 8192;  // tiled layout
    const half_t* wkl_b = wk_lo + (size_t)b * 64 * 8192;
    const half_t* vt_b  = vT    + (size_t)b * 64 * 8192;
    const int t0 = ks * NIT;

    // vt slot offset is dt-independent: slot = quad ^ (l15&3) ^ ((l15>>2)&3)
    const int vslot8 = (quad ^ (l15 & 3) ^ ((l15 >> 2) & 3)) * 8;

    // prologue: stage wk(0) hi+lo (8 DMA ops/wave)
    {
        const half_t* wh_t = wkh_b + (size_t)t0 * 8192;
        const half_t* wl_t = wkl_b + (size_t)t0 * 8192;
        #pragma unroll
        for (int i = 0; i < 4; ++i) {
            const int sg = i * 4 + wv;            // 16 segments of 1 KiB each
            dma16(wh_t + sg * 512 + lane * 8, s_wk_hi + sg * 512);
            dma16(wl_t + sg * 512 + lane * 8, s_wk_lo + sg * 512);
        }
    }

    for (int it = 0; it < NIT; ++it) {
        const bool pre = (it + 1 < NIT);

        // only wk(it) DMA outstanding here (all vt loads consumed in PV)
        asm volatile("s_waitcnt vmcnt(0)" ::: "memory");
        __builtin_amdgcn_s_barrier();        // (A) wk(it) resident
        asm volatile("" ::: "memory");

        // ---- S^T = wk . q^T : tiles [kt 16-keys][ct 16-qcols], hi/lo on wk
        float4_ S[2][2];
        S[0][0] = {0.f,0.f,0.f,0.f}; S[0][1] = {0.f,0.f,0.f,0.f};
        S[1][0] = {0.f,0.f,0.f,0.f}; S[1][1] = {0.f,0.f,0.f,0.f};
        __builtin_amdgcn_s_setprio(1);
        #pragma unroll
        for (int c = 0; c < 8; ++c)
            #pragma unroll
            for (int kt = 0; kt < 2; ++kt) {
                const int key = kt * 16 + l15;
                const int off = key * 256 + (((c * 4 + quad) ^ (key & 7)) * 8);
                half8 wh = *(const half8*)(s_wk_hi + off);
                half8 wl = *(const half8*)(s_wk_lo + off);
                #pragma unroll
                for (int ct = 0; ct < 2; ++ct) {
                    S[kt][ct] = __builtin_amdgcn_mfma_f32_16x16x32_f16(wh, qf[ct][c], S[kt][ct], 0, 0, 0);
                    S[kt][ct] = __builtin_amdgcn_mfma_f32_16x16x32_f16(wl, qf[ct][c], S[kt][ct], 0, 0, 0);
                }
            }
        __builtin_amdgcn_s_setprio(0);
        __builtin_amdgcn_sched_barrier(0);   // pin QK cluster + its lgkm waits
        __builtin_amdgcn_s_barrier();        // (B) all waves done reading wk(it)
        asm volatile("" ::: "memory");

        // wk(it+1) DMA into the just-freed planes; cover = softmax+PV+next-top
        if (pre) {
            const int ktn = t0 + it + 1;
            const half_t* wh_t = wkh_b + (size_t)ktn * 8192;
            const half_t* wl_t = wkl_b + (size_t)ktn * 8192;
            #pragma unroll
            for (int i = 0; i < 4; ++i) {
                const int sg = i * 4 + wv;
                dma16(wh_t + sg * 512 + lane * 8, s_wk_hi + sg * 512);
                dma16(wl_t + sg * 512 + lane * 8, s_wk_lo + sg * 512);
            }
        }

        // vt chunk0: dt 0..7 direct from L2 (streams under softmax)
        const half_t* vt_t = vt_b + (size_t)(t0 + it) * 8192;
        half8 vf0[8];
        #pragma unroll
        for (int dt = 0; dt < 8; ++dt)
            vf0[dt] = *(const half8*)(vt_t + (dt * 16 + l15) * 32 + vslot8);

        // ---- softmax (VALU, overlaps load flight); lane owns qcol ct*16+l15
        float mx0, mx1;
        {
            float a0 = fmaxf(fmaxf(S[0][0][0], S[0][0][1]), fmaxf(S[0][0][2], S[0][0][3]));
            float b0 = fmaxf(fmaxf(S[1][0][0], S[1][0][1]), fmaxf(S[1][0][2], S[1][0][3]));
            mx0 = fmaxf(a0, b0);
            mx0 = fmaxf(mx0, __shfl_xor(mx0, 16));
            mx0 = fmaxf(mx0, __shfl_xor(mx0, 32));
            float a1 = fmaxf(fmaxf(S[0][1][0], S[0][1][1]), fmaxf(S[0][1][2], S[0][1][3]));
            float b1 = fmaxf(fmaxf(S[1][1][0], S[1][1][1]), fmaxf(S[1][1][2], S[1][1][3]));
            mx1 = fmaxf(a1, b1);
            mx1 = fmaxf(mx1, __shfl_xor(mx1, 16));
            mx1 = fmaxf(mx1, __shfl_xor(mx1, 32));
        }
        // defer-rescale: keep frozen max while tile max within THR=8
        const int doresc = __any((mx0 > m_c[0] + 8.f) || (mx1 > m_c[1] + 8.f));
        float alpha0 = 1.f, alpha1 = 1.f;
        if (doresc) {
            float mn0 = fmaxf(m_c[0], mx0);
            float mn1 = fmaxf(m_c[1], mx1);
            alpha0 = __expf(m_c[0] - mn0);
            alpha1 = __expf(m_c[1] - mn1);
            m_c[0] = mn0; m_c[1] = mn1;
        }
        // P stays in registers: pf[ct] is directly the PV B-frag (producer-side
        // key permutation of vT).
        half8 pf[2];
        #pragma unroll
        for (int ct = 0; ct < 2; ++ct) {
            const float mm = m_c[ct];
            float rs = 0.f;
            #pragma unroll
            for (int r = 0; r < 4; ++r) {
                float p0 = __expf(S[0][ct][r] - mm);
                float p1 = __expf(S[1][ct][r] - mm);
                rs += p0 + p1;
                pf[ct][r]     = (half_t)p0;
                pf[ct][4 + r] = (half_t)p1;
            }
            rs += __shfl_xor(rs, 16);
            rs += __shfl_xor(rs, 32);
            l_c[ct] = l_c[ct] * (ct ? alpha1 : alpha0) + rs;
        }
        if (doresc) {
            #pragma unroll
            for (int dt = 0; dt < 16; ++dt)
                #pragma unroll
                for (int r = 0; r < 4; ++r) {
                    ctx[dt][0][r] *= alpha0;
                    ctx[dt][1][r] *= alpha1;
                }
        }

        // vt chunk1: dt 8..15 (streams under first-half PV)
        half8 vf1[8];
        #pragma unroll
        for (int dt = 0; dt < 8; ++dt)
            vf1[dt] = *(const half8*)(vt_t + ((dt + 8) * 16 + l15) * 32 + vslot8);

        // ---- ctx^T += vT_tile . P^T (compiler pipelines vmcnt on vf)
        __builtin_amdgcn_s_setprio(1);
        #pragma unroll
        for (int dt = 0; dt < 8; ++dt) {
            ctx[dt][0] = __builtin_amdgcn_mfma_f32_16x16x32_f16(vf0[dt], pf[0], ctx[dt][0], 0, 0, 0);
            ctx[dt][1] = __builtin_amdgcn_mfma_f32_16x16x32_f16(vf0[dt], pf[1], ctx[dt][1], 0, 0, 0);
        }
        #pragma unroll
        for (int dt = 0; dt < 8; ++dt) {
            ctx[8 + dt][0] = __builtin_amdgcn_mfma_f32_16x16x32_f16(vf1[dt], pf[0], ctx[8 + dt][0], 0, 0, 0);
            ctx[8 + dt][1] = __builtin_amdgcn_mfma_f32_16x16x32_f16(vf1[dt], pf[1], ctx[8 + dt][1], 0, 0, 0);
        }
        __builtin_amdgcn_s_setprio(0);
    }

    // epilogue: last B-barrier certified all waves past QK(last) -> wk LDS
    // free; PV used regs only. Per-wave private scr regions -> no extra sync.
    float rinv[2] = {1.0f / l_c[0], 1.0f / l_c[1]};
    float* sw = scr + wv * (32 * 68);       // [q 32][stride 68] f32
    half_t* pcs = pc + (size_t)ks * NROWS * 256;
    #pragma unroll
    for (int rd = 0; rd < 4; ++rd) {
        #pragma unroll
        for (int dtl = 0; dtl < 4; ++dtl) {
            const int dt = rd * 4 + dtl;
            #pragma unroll
            for (int ct = 0; ct < 2; ++ct)
                #pragma unroll
                for (int r = 0; r < 4; ++r)
                    sw[(ct * 16 + l15) * 68 + dtl * 16 + quad * 4 + r] = ctx[dt][ct][r] * rinv[ct];
        }
        #pragma unroll
        for (int i = 0; i < 8; ++i) {
            int g = lane + i * 64;
            int q = g >> 4, dc = g & 15;
            float4_ v4 = *(const float4_*)(sw + q * 68 + dc * 4);
            half4v h4;
            #pragma unroll
            for (int j = 0; j < 4; ++j) h4[j] = (half_t)v4[j];
            *(half4v*)(pcs + (size_t)(qbase + q) * 256 + rd * 64 + dc * 4) = h4;
        }
    }
    if (quad == 0) {
        #pragma unroll
        for (int ct = 0; ct < 2; ++ct) {
            const size_t row = qbase + ct * 16 + l15;
            pm[(size_t)ks * NROWS + row] = m_c[ct];
            pl[(size_t)ks * NROWS + row] = l_c[ct];
        }
    }
}

// ---------------------------------------------------------------------------
// Kernel 4: merge the KS k-split partials.
// ---------------------------------------------------------------------------
__global__ __launch_bounds__(256) void combine_kernel(
    const half_t* __restrict__ pc, const float* __restrict__ pm,
    const float* __restrict__ pl, float* __restrict__ out)
{
    const int t = threadIdx.x;
    const int row = blockIdx.x * 4 + (t >> 6);
    const int d0 = (t & 63) * 4;
    float m[KS], l[KS];
    float ms = -1e30f;
    #pragma unroll
    for (int i = 0; i < KS; ++i) {
        m[i] = pm[(size_t)i * NROWS + row];
        l[i] = pl[(size_t)i * NROWS + row];
        ms = fmaxf(ms, m[i]);
    }
    float w[KS], tot = 0.f;
    #pragma unroll
    for (int i = 0; i < KS; ++i) {
        w[i] = l[i] * __expf(m[i] - ms);
        tot += w[i];
    }
    float inv = 1.0f / tot;
    float4_ o = {0.f, 0.f, 0.f, 0.f};
    #pragma unroll
    for (int i = 0; i < KS; ++i) {
        half4v y = *(const half4v*)(pc + ((size_t)i * NROWS + row) * 256 + d0);
        float wi = w[i] * inv;
        #pragma unroll
        for (int j = 0; j < 4; ++j) o[j] += wi * (float)y[j];
    }
    *(float4_*)(out + (size_t)row * 256 + d0) = o;
}

// ---------------------------------------------------------------------------
extern "C" void kernel_launch(void* const* d_in, const int* in_sizes, int n_in,
                              void* d_out, int out_size, void* d_ws, size_t ws_size,
                              hipStream_t stream) {
    const float* x      = (const float*)d_in[0];
    const float* states = (const float*)d_in[1];
    const float* Wq     = (const float*)d_in[2];
    const float* bq     = (const float*)d_in[3];
    const float* Wk     = (const float*)d_in[4];
    const float* bk     = (const float*)d_in[5];
    const float* Wv     = (const float*)d_in[6];
    const float* bv     = (const float*)d_in[7];
    const float* Wa     = (const float*)d_in[8];
    const float* ba     = (const float*)d_in[9];
    float* out = (float*)d_out;

    char* ws = (char*)d_ws;
    size_t off = 0;
    auto alloc = [&](size_t bytes) -> void* {
        void* p = ws + off;
        off += (bytes + 255) & ~(size_t)255;
        return p;
    };
    half_t* Wq_hi = (half_t*)alloc(65536 * 2);
    half_t* Wq_lo = (half_t*)alloc(65536 * 2);
    half_t* Wc_hi = (half_t*)alloc(65536 * 2);
    half_t* Wc_lo = (half_t*)alloc(65536 * 2);
    half_t* Wv_hi = (half_t*)alloc(65536 * 2);
    float*  bc    = (float*)alloc(256 * 4);
    half_t* q_hi  = (half_t*)alloc((size_t)NROWS * 256 * 2);
    half_t* wk_hi = (half_t*)alloc((size_t)NROWS * 256 * 2);   // tiled layout
    half_t* wk_lo = (half_t*)alloc((size_t)NROWS * 256 * 2);   // tiled layout
    half_t* vT    = (half_t*)alloc((size_t)NROWS * 256 * 2);   // tiled layout
    half_t* pc    = (half_t*)alloc((size_t)KS * NROWS * 256 * 2);
    float*  pm    = (float*)alloc((size_t)KS * NROWS * 4);
    float*  pl    = (float*)alloc((size_t)KS * NROWS * 4);

    prep_kernel<<<256, 256, 0, stream>>>(Wq, Wk, Wv, Wa, bk, ba,
                                         Wq_hi, Wq_lo, Wc_hi, Wc_lo, Wv_hi, bc);
    linear_kernel<<<768, 256, 0, stream>>>(x, states,
                                           Wq_hi, Wq_lo, bq,
                                           Wc_hi, Wc_lo, bc,
                                           Wv_hi, bv,
                                           q_hi, wk_hi, wk_lo, vT);
    attn_kernel<<<8 * 16 * KS, 256, 0, stream>>>(q_hi, wk_hi, wk_lo, vT,
                                                 pc, pm, pl);
    combine_kernel<<<NROWS / 4, 256, 0, stream>>>(pc, pm, pl, out);
}

// Round 6
// 198.119 us; speedup vs baseline: 2.5458x; 1.3344x over previous
//
#include <hip/hip_runtime.h>
#include <cstdint>
#include <cstddef>

typedef _Float16 half_t;
typedef _Float16 half8 __attribute__((ext_vector_type(8)));
typedef _Float16 half4v __attribute__((ext_vector_type(4)));
typedef float float4_ __attribute__((ext_vector_type(4)));

#define NB 8
#define SEQ 2048
#define DIM 256
#define NROWS (NB*SEQ)   // 16384
#define KS 4             // k-split -> grid 512 = 2 blocks/CU
#define NIT 16           // (2048/KS)/32 key-tiles per block

// async global->LDS DMA, 16B per lane; LDS dest = wave-uniform base + lane*16
__device__ __forceinline__ void dma16(const half_t* g, half_t* l) {
    __builtin_amdgcn_global_load_lds(
        (const __attribute__((address_space(1))) void*)g,
        (__attribute__((address_space(3))) void*)l,
        16, 0, 0);
}

// ---------------------------------------------------------------------------
// Kernel 1: fold M = Wq^T @ Wa (scores = (x M^T? see below) ) and split
// weights to fp16 hi/lo.
//   scores[i,j] = q[i]·wk[j] = (x Wq^T + bq) Wa k^T + (q·ba)  -- the q·ba term
//   is a per-row constant -> softmax-invariant -> DROPPED.
//   q2 = x @ M^T + bq2 with M[d,m] = sum_e Wa[e,d]*Wq[e,m], bq2 = Wa^T bq.
//   k  = states @ Wk^T + bk (plain linear).
// ---------------------------------------------------------------------------
__global__ __launch_bounds__(256) void prep_kernel(
    const float* __restrict__ Wq, const float* __restrict__ Wk,
    const float* __restrict__ Wv, const float* __restrict__ Wa,
    const float* __restrict__ bq,
    half_t* __restrict__ M_hi, half_t* __restrict__ M_lo,
    half_t* __restrict__ Wk_hi, half_t* __restrict__ Wk_lo,
    half_t* __restrict__ Wv_hi, float* __restrict__ bq2)
{
    const int d = blockIdx.x;      // q2 out-dim
    const int m = threadIdx.x;     // in-dim
    const int idx = d * 256 + m;
    float acc = 0.f;
    for (int e = 0; e < 256; ++e)
        acc += Wa[e * 256 + d] * Wq[e * 256 + m];   // Wa[e,d] scalar-broadcast
    half_t h = (half_t)acc;
    M_hi[idx] = h;
    M_lo[idx] = (half_t)(acc - (float)h);
    float wk = Wk[idx];
    h = (half_t)wk;
    Wk_hi[idx] = h;
    Wk_lo[idx] = (half_t)(wk - (float)h);
    Wv_hi[idx] = (half_t)Wv[idx];
    if (m == 0) {
        float b2 = 0.f;
        for (int e = 0; e < 256; ++e) b2 += bq[e] * Wa[e * 256 + d];
        bq2[d] = b2;
    }
}

// ---------------------------------------------------------------------------
// Kernel 2: linears. seg0: q2 = x@M^T+bq2, hi plane only, row-major.
// seg1: k = states@Wk^T+bk, hi plane only, attn-tile-swizzled layout.
// seg2: v -> vT tile-swizzled + key-permuted for reg-P PV.
// Internal GEMMs keep the 3-MFMA hi/lo weight scheme for fp32-grade accuracy
// before the single fp16 output quantization.
// ---------------------------------------------------------------------------
__global__ __launch_bounds__(256, 2) void linear_kernel(
    const float* __restrict__ x, const float* __restrict__ states,
    const half_t* __restrict__ M_hi, const half_t* __restrict__ M_lo, const float* __restrict__ bq2,
    const half_t* __restrict__ Wk_hi, const half_t* __restrict__ Wk_lo, const float* __restrict__ bk,
    const half_t* __restrict__ Wv_hi, const float* __restrict__ bv,
    half_t* __restrict__ q2_hi,
    half_t* __restrict__ k_hi,
    half_t* __restrict__ vT)
{
    __shared__ half_t sB[2 * 64 * 256];   // weights hi+lo = 64 KiB; reused as repack buf
    half_t* sBh = sB;
    half_t* sBl = sB + 64 * 256;

    const int seg  = blockIdx.x >> 8;      // 0:q2 1:k 2:v
    const int t    = blockIdx.x & 255;
    const int tid  = threadIdx.x;
    const int lane = tid & 63;
    const int wv   = tid >> 6;
    const int quad = lane >> 4;
    const int l15  = lane & 15;
    const int rb   = t * 64;               // block row base
    const int r0   = rb + wv * 16;         // wave's 16 rows

    const float* src  = (seg == 0) ? x : states;
    const half_t* Bh  = (seg == 0) ? M_hi : (seg == 1) ? Wk_hi : Wv_hi;
    const half_t* Bl  = (seg == 0) ? M_lo : Wk_lo;
    const float* bias = (seg == 0) ? bq2 : (seg == 1) ? bk : bv;

    // A-frags direct from global: A[m=l15 -> row][k=c*32+quad*8+j], hi/lo split
    half8 ah[8], al[8];
    #pragma unroll
    for (int c = 0; c < 8; ++c) {
        const float* pa = src + (size_t)(r0 + l15) * 256 + c * 32 + quad * 8;
        float4_ u0 = *(const float4_*)pa;
        float4_ u1 = *(const float4_*)(pa + 4);
        #pragma unroll
        for (int j = 0; j < 4; ++j) {
            half_t hh = (half_t)u0[j];
            ah[c][j] = hh; al[c][j] = (half_t)(u0[j] - (float)hh);
            hh = (half_t)u1[j];
            ah[c][4 + j] = hh; al[c][4 + j] = (half_t)(u1[j] - (float)hh);
        }
    }

    float4_ acc[16];
    if (seg != 2) {
        #pragma unroll
        for (int nt = 0; nt < 16; ++nt) {
            float be = bias[nt * 16 + l15];
            acc[nt] = {be, be, be, be};
        }
    } else {
        #pragma unroll
        for (int et = 0; et < 16; ++et)
            #pragma unroll
            for (int r = 0; r < 4; ++r)
                acc[et][r] = bias[et * 16 + quad * 4 + r];
    }

    #pragma unroll
    for (int eg = 0; eg < 4; ++eg) {
        __syncthreads();
        // stage weights e-group [64 e][256 k], XOR-swizzled chunks
        #pragma unroll
        for (int i = 0; i < 8; ++i) {
            int g = tid + i * 256;             // 0..2047 chunks
            int e = g >> 5, c = g & 31;
            *(half8*)(sBh + e * 256 + ((c ^ (e & 7)) * 8)) =
                *(const half8*)(Bh + (size_t)(eg * 64 + e) * 256 + c * 8);
        }
        if (seg != 2) {
            #pragma unroll
            for (int i = 0; i < 8; ++i) {
                int g = tid + i * 256;
                int e = g >> 5, c = g & 31;
                *(half8*)(sBl + e * 256 + ((c ^ (e & 7)) * 8)) =
                    *(const half8*)(Bl + (size_t)(eg * 64 + e) * 256 + c * 8);
            }
        }
        __syncthreads();

        if (seg != 2) {
            #pragma unroll
            for (int ntl = 0; ntl < 4; ++ntl) {
                float4_ a = acc[eg * 4 + ntl];
                const int el = ntl * 16 + l15;
                #pragma unroll
                for (int c = 0; c < 8; ++c) {
                    int off = el * 256 + (((c * 4 + quad) ^ (el & 7)) * 8);
                    half8 bh = *(const half8*)(sBh + off);
                    half8 bl = *(const half8*)(sBl + off);
                    a = __builtin_amdgcn_mfma_f32_16x16x32_f16(ah[c], bh, a, 0, 0, 0);
                    a = __builtin_amdgcn_mfma_f32_16x16x32_f16(al[c], bh, a, 0, 0, 0);
                    a = __builtin_amdgcn_mfma_f32_16x16x32_f16(ah[c], bl, a, 0, 0, 0);
                }
                acc[eg * 4 + ntl] = a;
            }
        } else {
            // flipped: A = Wv tile (rows e), B = x rows -> D[e][row]
            #pragma unroll
            for (int ntl = 0; ntl < 4; ++ntl) {
                float4_ a = acc[eg * 4 + ntl];
                const int el = ntl * 16 + l15;
                #pragma unroll
                for (int c = 0; c < 8; ++c) {
                    int off = el * 256 + (((c * 4 + quad) ^ (el & 7)) * 8);
                    half8 aw = *(const half8*)(sBh + off);
                    a = __builtin_amdgcn_mfma_f32_16x16x32_f16(aw, ah[c], a, 0, 0, 0);
                }
                acc[eg * 4 + ntl] = a;
            }
        }
    }

    // epilogue: repack through LDS for coalesced half8 global stores
    __syncthreads();   // weights LDS no longer needed
    if (seg != 2) {
        half_t* R = sB;   // [64 rows][256]
        #pragma unroll
        for (int nt = 0; nt < 16; ++nt)
            #pragma unroll
            for (int r = 0; r < 4; ++r)
                R[(wv * 16 + quad * 4 + r) * 256 + nt * 16 + l15] = (half_t)acc[nt][r];
        __syncthreads();
        if (seg == 0) {
            // q2 hi, row-major (attn loads q2 frags straight to registers)
            for (int i = 0; i < 8; ++i) {
                int g = tid + i * 256;                 // 2048 chunks
                int row = g >> 5, cc = g & 31;
                *(half8*)(q2_hi + (size_t)(rb + row) * 256 + cc * 8) =
                    *(const half8*)(R + row * 256 + cc * 8);
            }
        } else {
            // k hi: tile-swizzled layout (tile=32 keys, 8192 elems)
            for (int i = 0; i < 8; ++i) {
                int g = tid + i * 256;
                int row = g >> 5, cc = g & 31;
                int s = row & 31;
                size_t dst = ((size_t)(rb + row) >> 5) * 8192 + s * 256 + ((cc ^ (s & 7)) * 8);
                *(half8*)(k_hi + dst) = *(const half8*)(R + row * 256 + cc * 8);
            }
        }
    } else {
        // vT repack: sV [d 256][s 64] stride 68, then tile-swizzled stores.
        // Key permutation: logical chunk q of a 32-key tile holds keys
        // {t32+4q+j}(j<4) and {t32+16+4q+(j-4)}(j>=4) -- matches the natural
        // per-lane P ownership of the attn QK^T output.
        half_t* sV = sB;
        #pragma unroll
        for (int et = 0; et < 16; ++et)
            #pragma unroll
            for (int r = 0; r < 4; ++r)
                sV[(et * 16 + quad * 4 + r) * 68 + wv * 16 + l15] = (half_t)acc[et][r];
        __syncthreads();
        const int b = rb >> 11, s0 = rb & 2047;
        for (int i = 0; i < 8; ++i) {
            int g = tid + i * 256;                 // 2048 chunks: d 256 x sc8 8
            int d = g >> 3, sc8 = g & 7;
            int kt = (s0 >> 5) + (sc8 >> 2);
            int q  = sc8 & 3;                      // logical key-chunk
            int t32 = (sc8 >> 2) * 32;
            int slot = q ^ (d & 3) ^ ((d >> 2) & 3);
            half4v a4 = *(const half4v*)(sV + d * 68 + t32 + q * 4);
            half4v b4 = *(const half4v*)(sV + d * 68 + t32 + 16 + q * 4);
            half8 hv;
            hv[0] = a4[0]; hv[1] = a4[1]; hv[2] = a4[2]; hv[3] = a4[3];
            hv[4] = b4[0]; hv[5] = b4[1]; hv[6] = b4[2]; hv[7] = b4[3];
            size_t dst = ((size_t)b * 64 + kt) * 8192 + d * 32 + slot * 8;
            *(half8*)(vT + dst) = hv;
        }
    }
}

// ---------------------------------------------------------------------------
// Kernel 3: flash attention with folded q2. Single-plane k (the Wa fold moved
// the precision burden to the resident q2 side; both sides hi-only in QK).
//   - QK = 32 MFMA/iter (was 64), 16 ds_read (was 32).
//   - LDS 64K: k dbuf (2x16K) + vt dbuf (2x16K) -> ONE barrier per iteration:
//     at top, vmcnt(0) drains DMA(it) (issued one full iteration ago),
//     barrier certifies all waves past (it-1) reads, then DMA(it+1) targets
//     the opposite buffers. No buffer is ever read and written concurrently.
//   - P in registers via producer-side key permutation of vT (unchanged).
//   - defer-rescale THR=8 (unchanged).
// Regs: ctx 128 + qf 64 + S 16 + pf 8 + misc ~= 240 <= 256 (no new live state
// vs the 73us round-2 kernel).
// ---------------------------------------------------------------------------
__global__ __launch_bounds__(256, 2) void attn_kernel(
    const half_t* __restrict__ q2_hi,
    const half_t* __restrict__ k_hi, const half_t* __restrict__ vT,
    half_t* __restrict__ pc, float* __restrict__ pm, float* __restrict__ pl)
{
    __shared__ __align__(16) unsigned char smem[64 * 1024];
    // K0 @0, K1 @16384, V0 @32768, V1 @49152
    float* scr = (float*)smem;              // epilogue overlay

    const int tid  = threadIdx.x;
    const int lane = tid & 63;
    const int wv   = tid >> 6;
    const int quad = lane >> 4;
    const int l15  = lane & 15;

    const int b  = blockIdx.x & 7;          // XCD-swizzle: batch per XCD
    const int qt = (blockIdx.x >> 3) & 15;  // q-tile 0..15 (128 rows each)
    const int ks = blockIdx.x >> 7;         // k-split quarter 0..3

    const int qbase = b * 2048 + qt * 128 + wv * 32;   // wave's 32 q-rows

    // q2 B-frags resident (hi plane): B[n=qcol][k=c*32+quad*8+j]
    half8 qf[2][8];
    #pragma unroll
    for (int ct = 0; ct < 2; ++ct)
        #pragma unroll
        for (int c = 0; c < 8; ++c)
            qf[ct][c] = *(const half8*)(q2_hi +
                (size_t)(qbase + ct * 16 + l15) * 256 + c * 32 + quad * 8);

    float4_ ctx[16][2];
    #pragma unroll
    for (int dt = 0; dt < 16; ++dt) {
        ctx[dt][0] = {0.f, 0.f, 0.f, 0.f};
        ctx[dt][1] = {0.f, 0.f, 0.f, 0.f};
    }
    float m_c[2] = {-1e30f, -1e30f};
    float l_c[2] = {0.f, 0.f};

    const half_t* kh_b = k_hi + (size_t)b * 64 * 8192;   // tiled layout
    const half_t* vt_b = vT   + (size_t)b * 64 * 8192;
    const int t0 = ks * NIT;

    // vt slot is dt-independent: slot = quad ^ (l15&3) ^ ((l15>>2)&3)
    const int vslot8 = (quad ^ (l15 & 3) ^ ((l15 >> 2) & 3)) * 8;

    // prologue: stage k(0)->K0, vt(0)->V0 (8 DMA ops/wave)
    {
        const half_t* kt_ = kh_b + (size_t)t0 * 8192;
        const half_t* vt_ = vt_b + (size_t)t0 * 8192;
        #pragma unroll
        for (int i = 0; i < 4; ++i) {
            const int sg = i * 4 + wv;            // 16 segments of 1 KiB each
            dma16(kt_ + sg * 512 + lane * 8, (half_t*)smem + sg * 512);
            dma16(vt_ + sg * 512 + lane * 8, (half_t*)(smem + 32768) + sg * 512);
        }
    }

    for (int it = 0; it < NIT; ++it) {
        half_t* s_k  = (half_t*)(smem + ((it & 1) << 14));
        half_t* s_v  = (half_t*)(smem + 32768 + ((it & 1) << 14));
        half_t* s_kn = (half_t*)(smem + (((it + 1) & 1) << 14));
        half_t* s_vn = (half_t*)(smem + 32768 + (((it + 1) & 1) << 14));
        const bool pre = (it + 1 < NIT);

        // outstanding here: DMA(it) only (issued one full iteration ago)
        asm volatile("s_waitcnt vmcnt(0)" ::: "memory");
        __builtin_amdgcn_s_barrier();        // (it) data resident; (it-1) reads done
        asm volatile("" ::: "memory");

        if (pre) {
            const half_t* kt_ = kh_b + (size_t)(t0 + it + 1) * 8192;
            const half_t* vt_ = vt_b + (size_t)(t0 + it + 1) * 8192;
            #pragma unroll
            for (int i = 0; i < 4; ++i) {
                const int sg = i * 4 + wv;
                dma16(kt_ + sg * 512 + lane * 8, s_kn + sg * 512);
                dma16(vt_ + sg * 512 + lane * 8, s_vn + sg * 512);
            }
        }

        // ---- S^T = k . q2^T : tiles [kt 16-keys][ct 16-qcols], single-plane
        float4_ S[2][2];
        S[0][0] = {0.f,0.f,0.f,0.f}; S[0][1] = {0.f,0.f,0.f,0.f};
        S[1][0] = {0.f,0.f,0.f,0.f}; S[1][1] = {0.f,0.f,0.f,0.f};
        __builtin_amdgcn_s_setprio(1);
        #pragma unroll
        for (int c = 0; c < 8; ++c)
            #pragma unroll
            for (int kt = 0; kt < 2; ++kt) {
                const int key = kt * 16 + l15;
                const int off = key * 256 + (((c * 4 + quad) ^ (key & 7)) * 8);
                half8 kf = *(const half8*)(s_k + off);
                #pragma unroll
                for (int ct = 0; ct < 2; ++ct)
                    S[kt][ct] = __builtin_amdgcn_mfma_f32_16x16x32_f16(kf, qf[ct][c], S[kt][ct], 0, 0, 0);
            }
        __builtin_amdgcn_s_setprio(0);
        __builtin_amdgcn_sched_barrier(0);   // pin QK cluster + its lgkm waits

        // ---- softmax (VALU, overlaps DMA flight); lane owns qcol ct*16+l15
        float mx0, mx1;
        {
            float a0 = fmaxf(fmaxf(S[0][0][0], S[0][0][1]), fmaxf(S[0][0][2], S[0][0][3]));
            float b0 = fmaxf(fmaxf(S[1][0][0], S[1][0][1]), fmaxf(S[1][0][2], S[1][0][3]));
            mx0 = fmaxf(a0, b0);
            mx0 = fmaxf(mx0, __shfl_xor(mx0, 16));
            mx0 = fmaxf(mx0, __shfl_xor(mx0, 32));
            float a1 = fmaxf(fmaxf(S[0][1][0], S[0][1][1]), fmaxf(S[0][1][2], S[0][1][3]));
            float b1 = fmaxf(fmaxf(S[1][1][0], S[1][1][1]), fmaxf(S[1][1][2], S[1][1][3]));
            mx1 = fmaxf(a1, b1);
            mx1 = fmaxf(mx1, __shfl_xor(mx1, 16));
            mx1 = fmaxf(mx1, __shfl_xor(mx1, 32));
        }
        // defer-rescale: keep frozen max while tile max within THR=8
        const int doresc = __any((mx0 > m_c[0] + 8.f) || (mx1 > m_c[1] + 8.f));
        float alpha0 = 1.f, alpha1 = 1.f;
        if (doresc) {
            float mn0 = fmaxf(m_c[0], mx0);
            float mn1 = fmaxf(m_c[1], mx1);
            alpha0 = __expf(m_c[0] - mn0);
            alpha1 = __expf(m_c[1] - mn1);
            m_c[0] = mn0; m_c[1] = mn1;
        }
        // P stays in registers: pf[ct] is directly the PV B-frag (producer-side
        // key permutation of vT).
        half8 pf[2];
        #pragma unroll
        for (int ct = 0; ct < 2; ++ct) {
            const float mm = m_c[ct];
            float rs = 0.f;
            #pragma unroll
            for (int r = 0; r < 4; ++r) {
                float p0 = __expf(S[0][ct][r] - mm);
                float p1 = __expf(S[1][ct][r] - mm);
                rs += p0 + p1;
                pf[ct][r]     = (half_t)p0;
                pf[ct][4 + r] = (half_t)p1;
            }
            rs += __shfl_xor(rs, 16);
            rs += __shfl_xor(rs, 32);
            l_c[ct] = l_c[ct] * (ct ? alpha1 : alpha0) + rs;
        }
        if (doresc) {
            #pragma unroll
            for (int dt = 0; dt < 16; ++dt)
                #pragma unroll
                for (int r = 0; r < 4; ++r) {
                    ctx[dt][0][r] *= alpha0;
                    ctx[dt][1][r] *= alpha1;
                }
        }

        // ---- ctx^T += vT_tile . P^T
        __builtin_amdgcn_s_setprio(1);
        #pragma unroll
        for (int dt = 0; dt < 16; ++dt) {
            half8 vf = *(const half8*)(s_v + (dt * 16 + l15) * 32 + vslot8);
            ctx[dt][0] = __builtin_amdgcn_mfma_f32_16x16x32_f16(vf, pf[0], ctx[dt][0], 0, 0, 0);
            ctx[dt][1] = __builtin_amdgcn_mfma_f32_16x16x32_f16(vf, pf[1], ctx[dt][1], 0, 0, 0);
        }
        __builtin_amdgcn_s_setprio(0);
        __builtin_amdgcn_sched_barrier(0);   // pin PV cluster + its lgkm waits
    }

    __syncthreads();   // all waves past final LDS reads; all DMA drained

    // epilogue: normalized partial context (fp16) via per-wave LDS transpose
    float rinv[2] = {1.0f / l_c[0], 1.0f / l_c[1]};
    float* sw = scr + wv * (32 * 68);       // [q 32][stride 68] f32
    half_t* pcs = pc + (size_t)ks * NROWS * 256;
    #pragma unroll
    for (int rd = 0; rd < 4; ++rd) {
        #pragma unroll
        for (int dtl = 0; dtl < 4; ++dtl) {
            const int dt = rd * 4 + dtl;
            #pragma unroll
            for (int ct = 0; ct < 2; ++ct)
                #pragma unroll
                for (int r = 0; r < 4; ++r)
                    sw[(ct * 16 + l15) * 68 + dtl * 16 + quad * 4 + r] = ctx[dt][ct][r] * rinv[ct];
        }
        #pragma unroll
        for (int i = 0; i < 8; ++i) {
            int g = lane + i * 64;
            int q = g >> 4, dc = g & 15;
            float4_ v4 = *(const float4_*)(sw + q * 68 + dc * 4);
            half4v h4;
            #pragma unroll
            for (int j = 0; j < 4; ++j) h4[j] = (half_t)v4[j];
            *(half4v*)(pcs + (size_t)(qbase + q) * 256 + rd * 64 + dc * 4) = h4;
        }
    }
    if (quad == 0) {
        #pragma unroll
        for (int ct = 0; ct < 2; ++ct) {
            const size_t row = qbase + ct * 16 + l15;
            pm[(size_t)ks * NROWS + row] = m_c[ct];
            pl[(size_t)ks * NROWS + row] = l_c[ct];
        }
    }
}

// ---------------------------------------------------------------------------
// Kernel 4: merge the KS k-split partials.
// ---------------------------------------------------------------------------
__global__ __launch_bounds__(256) void combine_kernel(
    const half_t* __restrict__ pc, const float* __restrict__ pm,
    const float* __restrict__ pl, float* __restrict__ out)
{
    const int t = threadIdx.x;
    const int row = blockIdx.x * 4 + (t >> 6);
    const int d0 = (t & 63) * 4;
    float m[KS], l[KS];
    float ms = -1e30f;
    #pragma unroll
    for (int i = 0; i < KS; ++i) {
        m[i] = pm[(size_t)i * NROWS + row];
        l[i] = pl[(size_t)i * NROWS + row];
        ms = fmaxf(ms, m[i]);
    }
    float w[KS], tot = 0.f;
    #pragma unroll
    for (int i = 0; i < KS; ++i) {
        w[i] = l[i] * __expf(m[i] - ms);
        tot += w[i];
    }
    float inv = 1.0f / tot;
    float4_ o = {0.f, 0.f, 0.f, 0.f};
    #pragma unroll
    for (int i = 0; i < KS; ++i) {
        half4v y = *(const half4v*)(pc + ((size_t)i * NROWS + row) * 256 + d0);
        float wi = w[i] * inv;
        #pragma unroll
        for (int j = 0; j < 4; ++j) o[j] += wi * (float)y[j];
    }
    *(float4_*)(out + (size_t)row * 256 + d0) = o;
}

// ---------------------------------------------------------------------------
extern "C" void kernel_launch(void* const* d_in, const int* in_sizes, int n_in,
                              void* d_out, int out_size, void* d_ws, size_t ws_size,
                              hipStream_t stream) {
    const float* x      = (const float*)d_in[0];
    const float* states = (const float*)d_in[1];
    const float* Wq     = (const float*)d_in[2];
    const float* bq     = (const float*)d_in[3];
    const float* Wk     = (const float*)d_in[4];
    const float* bk     = (const float*)d_in[5];
    const float* Wv     = (const float*)d_in[6];
    const float* bv     = (const float*)d_in[7];
    const float* Wa     = (const float*)d_in[8];
    // ba (d_in[9]) contributes a per-row constant to scores -> softmax-invariant -> unused.
    float* out = (float*)d_out;

    char* ws = (char*)d_ws;
    size_t off = 0;
    auto alloc = [&](size_t bytes) -> void* {
        void* p = ws + off;
        off += (bytes + 255) & ~(size_t)255;
        return p;
    };
    half_t* M_hi  = (half_t*)alloc(65536 * 2);
    half_t* M_lo  = (half_t*)alloc(65536 * 2);
    half_t* Wk_hi = (half_t*)alloc(65536 * 2);
    half_t* Wk_lo = (half_t*)alloc(65536 * 2);
    half_t* Wv_hi = (half_t*)alloc(65536 * 2);
    float*  bq2   = (float*)alloc(256 * 4);
    half_t* q2_hi = (half_t*)alloc((size_t)NROWS * 256 * 2);
    half_t* k_hi  = (half_t*)alloc((size_t)NROWS * 256 * 2);   // tiled layout
    half_t* vT    = (half_t*)alloc((size_t)NROWS * 256 * 2);   // tiled layout
    half_t* pc    = (half_t*)alloc((size_t)KS * NROWS * 256 * 2);
    float*  pm    = (float*)alloc((size_t)KS * NROWS * 4);
    float*  pl    = (float*)alloc((size_t)KS * NROWS * 4);

    prep_kernel<<<256, 256, 0, stream>>>(Wq, Wk, Wv, Wa, bq,
                                         M_hi, M_lo, Wk_hi, Wk_lo, Wv_hi, bq2);
    linear_kernel<<<768, 256, 0, stream>>>(x, states,
                                           M_hi, M_lo, bq2,
                                           Wk_hi, Wk_lo, bk,
                                           Wv_hi, bv,
                                           q2_hi, k_hi, vT);
    attn_kernel<<<8 * 16 * KS, 256, 0, stream>>>(q2_hi, k_hi, vT,
                                                 pc, pm, pl);
    combine_kernel<<<NROWS / 4, 256, 0, stream>>>(pc, pm, pl, out);
}

// Round 7
// 196.770 us; speedup vs baseline: 2.5632x; 1.0069x over previous
//
#include <hip/hip_runtime.h>
#include <cstdint>
#include <cstddef>

typedef _Float16 half_t;
typedef _Float16 half8 __attribute__((ext_vector_type(8)));
typedef _Float16 half4v __attribute__((ext_vector_type(4)));
typedef float float4_ __attribute__((ext_vector_type(4)));

#define NB 8
#define SEQ 2048
#define DIM 256
#define NROWS (NB*SEQ)   // 16384
#define KS 4             // k-split -> grid 512 = 2 blocks/CU
#define NIT 16           // (2048/KS)/32 key-tiles per block

// async global->LDS DMA, 16B per lane; LDS dest = wave-uniform base + lane*16
__device__ __forceinline__ void dma16(const half_t* g, half_t* l) {
    __builtin_amdgcn_global_load_lds(
        (const __attribute__((address_space(1))) void*)g,
        (__attribute__((address_space(3))) void*)l,
        16, 0, 0);
}

// ---------------------------------------------------------------------------
// Kernel 1: fold M = Wq^T @ Wa; scores = q·wk = (x M^T + bq2)·k^T + const_row
// (const row = q·ba is softmax-invariant -> dropped). Split planes fp16 hi/lo.
// ---------------------------------------------------------------------------
__global__ __launch_bounds__(256) void prep_kernel(
    const float* __restrict__ Wq, const float* __restrict__ Wk,
    const float* __restrict__ Wv, const float* __restrict__ Wa,
    const float* __restrict__ bq,
    half_t* __restrict__ M_hi, half_t* __restrict__ M_lo,
    half_t* __restrict__ Wk_hi, half_t* __restrict__ Wk_lo,
    half_t* __restrict__ Wv_hi, float* __restrict__ bq2)
{
    const int d = blockIdx.x;      // q2 out-dim
    const int m = threadIdx.x;     // in-dim
    const int idx = d * 256 + m;
    float acc = 0.f;
    for (int e = 0; e < 256; ++e)
        acc += Wa[e * 256 + d] * Wq[e * 256 + m];   // Wa[e,d] scalar-broadcast
    half_t h = (half_t)acc;
    M_hi[idx] = h;
    M_lo[idx] = (half_t)(acc - (float)h);
    float wk = Wk[idx];
    h = (half_t)wk;
    Wk_hi[idx] = h;
    Wk_lo[idx] = (half_t)(wk - (float)h);
    Wv_hi[idx] = (half_t)Wv[idx];
    if (m == 0) {
        float b2 = 0.f;
        for (int e = 0; e < 256; ++e) b2 += bq[e] * Wa[e * 256 + d];
        bq2[d] = b2;
    }
}

// ---------------------------------------------------------------------------
// Kernel 2: linears. seg0: q2 = x@M^T+bq2, hi plane only, row-major.
// seg1: k = states@Wk^T+bk, hi plane only, attn-tile-swizzled layout.
// seg2: v -> vT tile-swizzled + key-permuted for reg-P PV.
// ---------------------------------------------------------------------------
__global__ __launch_bounds__(256, 2) void linear_kernel(
    const float* __restrict__ x, const float* __restrict__ states,
    const half_t* __restrict__ M_hi, const half_t* __restrict__ M_lo, const float* __restrict__ bq2,
    const half_t* __restrict__ Wk_hi, const half_t* __restrict__ Wk_lo, const float* __restrict__ bk,
    const half_t* __restrict__ Wv_hi, const float* __restrict__ bv,
    half_t* __restrict__ q2_hi,
    half_t* __restrict__ k_hi,
    half_t* __restrict__ vT)
{
    __shared__ half_t sB[2 * 64 * 256];   // weights hi+lo = 64 KiB; reused as repack buf
    half_t* sBh = sB;
    half_t* sBl = sB + 64 * 256;

    const int seg  = blockIdx.x >> 8;      // 0:q2 1:k 2:v
    const int t    = blockIdx.x & 255;
    const int tid  = threadIdx.x;
    const int lane = tid & 63;
    const int wv   = tid >> 6;
    const int quad = lane >> 4;
    const int l15  = lane & 15;
    const int rb   = t * 64;               // block row base
    const int r0   = rb + wv * 16;         // wave's 16 rows

    const float* src  = (seg == 0) ? x : states;
    const half_t* Bh  = (seg == 0) ? M_hi : (seg == 1) ? Wk_hi : Wv_hi;
    const half_t* Bl  = (seg == 0) ? M_lo : Wk_lo;
    const float* bias = (seg == 0) ? bq2 : (seg == 1) ? bk : bv;

    // A-frags direct from global: A[m=l15 -> row][k=c*32+quad*8+j], hi/lo split
    half8 ah[8], al[8];
    #pragma unroll
    for (int c = 0; c < 8; ++c) {
        const float* pa = src + (size_t)(r0 + l15) * 256 + c * 32 + quad * 8;
        float4_ u0 = *(const float4_*)pa;
        float4_ u1 = *(const float4_*)(pa + 4);
        #pragma unroll
        for (int j = 0; j < 4; ++j) {
            half_t hh = (half_t)u0[j];
            ah[c][j] = hh; al[c][j] = (half_t)(u0[j] - (float)hh);
            hh = (half_t)u1[j];
            ah[c][4 + j] = hh; al[c][4 + j] = (half_t)(u1[j] - (float)hh);
        }
    }

    float4_ acc[16];
    if (seg != 2) {
        #pragma unroll
        for (int nt = 0; nt < 16; ++nt) {
            float be = bias[nt * 16 + l15];
            acc[nt] = {be, be, be, be};
        }
    } else {
        #pragma unroll
        for (int et = 0; et < 16; ++et)
            #pragma unroll
            for (int r = 0; r < 4; ++r)
                acc[et][r] = bias[et * 16 + quad * 4 + r];
    }

    #pragma unroll
    for (int eg = 0; eg < 4; ++eg) {
        __syncthreads();
        // stage weights e-group [64 e][256 k], XOR-swizzled chunks
        #pragma unroll
        for (int i = 0; i < 8; ++i) {
            int g = tid + i * 256;             // 0..2047 chunks
            int e = g >> 5, c = g & 31;
            *(half8*)(sBh + e * 256 + ((c ^ (e & 7)) * 8)) =
                *(const half8*)(Bh + (size_t)(eg * 64 + e) * 256 + c * 8);
        }
        if (seg != 2) {
            #pragma unroll
            for (int i = 0; i < 8; ++i) {
                int g = tid + i * 256;
                int e = g >> 5, c = g & 31;
                *(half8*)(sBl + e * 256 + ((c ^ (e & 7)) * 8)) =
                    *(const half8*)(Bl + (size_t)(eg * 64 + e) * 256 + c * 8);
            }
        }
        __syncthreads();

        if (seg != 2) {
            #pragma unroll
            for (int ntl = 0; ntl < 4; ++ntl) {
                float4_ a = acc[eg * 4 + ntl];
                const int el = ntl * 16 + l15;
                #pragma unroll
                for (int c = 0; c < 8; ++c) {
                    int off = el * 256 + (((c * 4 + quad) ^ (el & 7)) * 8);
                    half8 bh = *(const half8*)(sBh + off);
                    half8 bl = *(const half8*)(sBl + off);
                    a = __builtin_amdgcn_mfma_f32_16x16x32_f16(ah[c], bh, a, 0, 0, 0);
                    a = __builtin_amdgcn_mfma_f32_16x16x32_f16(al[c], bh, a, 0, 0, 0);
                    a = __builtin_amdgcn_mfma_f32_16x16x32_f16(ah[c], bl, a, 0, 0, 0);
                }
                acc[eg * 4 + ntl] = a;
            }
        } else {
            // flipped: A = Wv tile (rows e), B = x rows -> D[e][row]
            #pragma unroll
            for (int ntl = 0; ntl < 4; ++ntl) {
                float4_ a = acc[eg * 4 + ntl];
                const int el = ntl * 16 + l15;
                #pragma unroll
                for (int c = 0; c < 8; ++c) {
                    int off = el * 256 + (((c * 4 + quad) ^ (el & 7)) * 8);
                    half8 aw = *(const half8*)(sBh + off);
                    a = __builtin_amdgcn_mfma_f32_16x16x32_f16(aw, ah[c], a, 0, 0, 0);
                }
                acc[eg * 4 + ntl] = a;
            }
        }
    }

    // epilogue: repack through LDS for coalesced half8 global stores
    __syncthreads();   // weights LDS no longer needed
    if (seg != 2) {
        half_t* R = sB;   // [64 rows][256]
        #pragma unroll
        for (int nt = 0; nt < 16; ++nt)
            #pragma unroll
            for (int r = 0; r < 4; ++r)
                R[(wv * 16 + quad * 4 + r) * 256 + nt * 16 + l15] = (half_t)acc[nt][r];
        __syncthreads();
        if (seg == 0) {
            // q2 hi, row-major (attn loads q2 frags straight to registers)
            for (int i = 0; i < 8; ++i) {
                int g = tid + i * 256;                 // 2048 chunks
                int row = g >> 5, cc = g & 31;
                *(half8*)(q2_hi + (size_t)(rb + row) * 256 + cc * 8) =
                    *(const half8*)(R + row * 256 + cc * 8);
            }
        } else {
            // k hi: tile-swizzled layout (tile=32 keys, 8192 elems)
            for (int i = 0; i < 8; ++i) {
                int g = tid + i * 256;
                int row = g >> 5, cc = g & 31;
                int s = row & 31;
                size_t dst = ((size_t)(rb + row) >> 5) * 8192 + s * 256 + ((cc ^ (s & 7)) * 8);
                *(half8*)(k_hi + dst) = *(const half8*)(R + row * 256 + cc * 8);
            }
        }
    } else {
        // vT repack: sV [d 256][s 64] stride 68, then tile-swizzled stores.
        // Key permutation: logical chunk q of a 32-key tile holds keys
        // {t32+4q+j}(j<4) and {t32+16+4q+(j-4)}(j>=4) -- matches the natural
        // per-lane P ownership of the attn QK^T output.
        half_t* sV = sB;
        #pragma unroll
        for (int et = 0; et < 16; ++et)
            #pragma unroll
            for (int r = 0; r < 4; ++r)
                sV[(et * 16 + quad * 4 + r) * 68 + wv * 16 + l15] = (half_t)acc[et][r];
        __syncthreads();
        const int b = rb >> 11, s0 = rb & 2047;
        for (int i = 0; i < 8; ++i) {
            int g = tid + i * 256;                 // 2048 chunks: d 256 x sc8 8
            int d = g >> 3, sc8 = g & 7;
            int kt = (s0 >> 5) + (sc8 >> 2);
            int q  = sc8 & 3;                      // logical key-chunk
            int t32 = (sc8 >> 2) * 32;
            int slot = q ^ (d & 3) ^ ((d >> 2) & 3);
            half4v a4 = *(const half4v*)(sV + d * 68 + t32 + q * 4);
            half4v b4 = *(const half4v*)(sV + d * 68 + t32 + 16 + q * 4);
            half8 hv;
            hv[0] = a4[0]; hv[1] = a4[1]; hv[2] = a4[2]; hv[3] = a4[3];
            hv[4] = b4[0]; hv[5] = b4[1]; hv[6] = b4[2]; hv[7] = b4[3];
            size_t dst = ((size_t)b * 64 + kt) * 8192 + d * 32 + slot * 8;
            *(half8*)(vT + dst) = hv;
        }
    }
}

// ---------------------------------------------------------------------------
// Kernel 3: flash attention, CROSS-ITERATION PIPELINE: PV(it-1) executes
// inside body(it), interleaved with softmax(it) (independent data) so the
// serial softmax chain hides under 32 independent PV MFMAs.
//   invariant: end of body(it): ctx = sum_{j<=it-1} exp(S_j - m(it))·V_j
//   (PV(it-1) lands at scale m(it-1), THEN ctx *= alpha(it)).
// LDS 64K: k dbuf (2x16K) + vt dbuf (2x16K). Two barriers/iter:
//   B1 (top, after vmcnt(4)): k(it) + vt(it-1) resident globally.
//     -> issue k(it+1) (full-iter cover)
//   B2 (after PV(it-1), sched_barrier-pinned): PV reads done globally
//     -> issue vt(it+1) (1.5-iter cover)
// FIFO per wave: ... k(it)x4, vt(it)x4, k(it+1)x4, ... -> vmcnt(4) at top
// retires exactly {vt(it-1), k(it)}. Regs: +8 VGPR (pfp) vs round-6.
// ---------------------------------------------------------------------------
__global__ __launch_bounds__(256, 2) void attn_kernel(
    const half_t* __restrict__ q2_hi,
    const half_t* __restrict__ k_hi, const half_t* __restrict__ vT,
    half_t* __restrict__ pc, float* __restrict__ pm, float* __restrict__ pl)
{
    __shared__ __align__(16) unsigned char smem[64 * 1024];
    // K0 @0, K1 @16384, V0 @32768, V1 @49152
    float* scr = (float*)smem;              // epilogue overlay (bytes < 34816)

    const int tid  = threadIdx.x;
    const int lane = tid & 63;
    const int wv   = tid >> 6;
    const int quad = lane >> 4;
    const int l15  = lane & 15;

    const int b  = blockIdx.x & 7;          // XCD-swizzle: batch per XCD
    const int qt = (blockIdx.x >> 3) & 15;  // q-tile 0..15 (128 rows each)
    const int ks = blockIdx.x >> 7;         // k-split quarter 0..3

    const int qbase = b * 2048 + qt * 128 + wv * 32;   // wave's 32 q-rows

    // q2 B-frags resident (hi plane): B[n=qcol][k=c*32+quad*8+j]
    half8 qf[2][8];
    #pragma unroll
    for (int ct = 0; ct < 2; ++ct)
        #pragma unroll
        for (int c = 0; c < 8; ++c)
            qf[ct][c] = *(const half8*)(q2_hi +
                (size_t)(qbase + ct * 16 + l15) * 256 + c * 32 + quad * 8);

    float4_ ctx[16][2];
    #pragma unroll
    for (int dt = 0; dt < 16; ++dt) {
        ctx[dt][0] = {0.f, 0.f, 0.f, 0.f};
        ctx[dt][1] = {0.f, 0.f, 0.f, 0.f};
    }
    float m_c[2] = {-1e30f, -1e30f};
    float l_c[2] = {0.f, 0.f};

    const half_t* kh_b = k_hi + (size_t)b * 64 * 8192;   // tiled layout
    const half_t* vt_b = vT   + (size_t)b * 64 * 8192;
    const int t0 = ks * NIT;

    // vt slot is dt-independent: slot = quad ^ (l15&3) ^ ((l15>>2)&3)
    const int vslot8 = (quad ^ (l15 & 3) ^ ((l15 >> 2) & 3)) * 8;

    // prologue: k(0)->K0 (group 1), then vt(0)->V0 (group 2) -- FIFO order
    // matters for the counted waits.
    {
        const half_t* kt_ = kh_b + (size_t)t0 * 8192;
        #pragma unroll
        for (int i = 0; i < 4; ++i) {
            const int sg = i * 4 + wv;            // 16 segments of 1 KiB each
            dma16(kt_ + sg * 512 + lane * 8, (half_t*)smem + sg * 512);
        }
        const half_t* vt_ = vt_b + (size_t)t0 * 8192;
        #pragma unroll
        for (int i = 0; i < 4; ++i) {
            const int sg = i * 4 + wv;
            dma16(vt_ + sg * 512 + lane * 8, (half_t*)(smem + 32768) + sg * 512);
        }
    }

    half8 pfp[2];   // pf from previous iteration (unused at it==0)
    #pragma unroll
    for (int ct = 0; ct < 2; ++ct)
        #pragma unroll
        for (int j = 0; j < 8; ++j) pfp[ct][j] = (half_t)0;

    for (int it = 0; it < NIT; ++it) {
        half_t* s_k  = (half_t*)(smem + ((it & 1) << 14));                // k(it)
        half_t* s_vP = (half_t*)(smem + 32768 + (((it + 1) & 1) << 14));  // vt(it-1)
        const bool pre = (it + 1 < NIT);

        // retires {vt(it-1), k(it)}; leaves vt(it) in flight
        asm volatile("s_waitcnt vmcnt(4)" ::: "memory");
        __builtin_amdgcn_s_barrier();        // B1
        asm volatile("" ::: "memory");

        // k(it+1) into the other k-buffer (safe: k(it-1) reads done globally
        // at B2(it-1) < B1(it)); cover = full iteration.
        if (pre) {
            const half_t* kt_ = kh_b + (size_t)(t0 + it + 1) * 8192;
            half_t* kdst = (half_t*)(smem + (((it + 1) & 1) << 14));
            #pragma unroll
            for (int i = 0; i < 4; ++i) {
                const int sg = i * 4 + wv;
                dma16(kt_ + sg * 512 + lane * 8, kdst + sg * 512);
            }
        }

        // ---- S^T = k . q2^T : tiles [kt 16-keys][ct 16-qcols]
        float4_ S[2][2];
        S[0][0] = {0.f,0.f,0.f,0.f}; S[0][1] = {0.f,0.f,0.f,0.f};
        S[1][0] = {0.f,0.f,0.f,0.f}; S[1][1] = {0.f,0.f,0.f,0.f};
        __builtin_amdgcn_s_setprio(1);
        #pragma unroll
        for (int c = 0; c < 8; ++c)
            #pragma unroll
            for (int kt = 0; kt < 2; ++kt) {
                const int key = kt * 16 + l15;
                const int off = key * 256 + (((c * 4 + quad) ^ (key & 7)) * 8);
                half8 kf = *(const half8*)(s_k + off);
                #pragma unroll
                for (int ct = 0; ct < 2; ++ct)
                    S[kt][ct] = __builtin_amdgcn_mfma_f32_16x16x32_f16(kf, qf[ct][c], S[kt][ct], 0, 0, 0);
            }
        __builtin_amdgcn_s_setprio(0);

        // ---- tile max + defer-rescale decision (THR=8)
        float mx0, mx1;
        {
            float a0 = fmaxf(fmaxf(S[0][0][0], S[0][0][1]), fmaxf(S[0][0][2], S[0][0][3]));
            float b0 = fmaxf(fmaxf(S[1][0][0], S[1][0][1]), fmaxf(S[1][0][2], S[1][0][3]));
            mx0 = fmaxf(a0, b0);
            mx0 = fmaxf(mx0, __shfl_xor(mx0, 16));
            mx0 = fmaxf(mx0, __shfl_xor(mx0, 32));
            float a1 = fmaxf(fmaxf(S[0][1][0], S[0][1][1]), fmaxf(S[0][1][2], S[0][1][3]));
            float b1 = fmaxf(fmaxf(S[1][1][0], S[1][1][1]), fmaxf(S[1][1][2], S[1][1][3]));
            mx1 = fmaxf(a1, b1);
            mx1 = fmaxf(mx1, __shfl_xor(mx1, 16));
            mx1 = fmaxf(mx1, __shfl_xor(mx1, 32));
        }
        const int doresc = __any((mx0 > m_c[0] + 8.f) || (mx1 > m_c[1] + 8.f));
        float alpha0 = 1.f, alpha1 = 1.f;
        if (doresc) {
            float mn0 = fmaxf(m_c[0], mx0);
            float mn1 = fmaxf(m_c[1], mx1);
            alpha0 = __expf(m_c[0] - mn0);
            alpha1 = __expf(m_c[1] - mn1);
            m_c[0] = mn0; m_c[1] = mn1;
        }

        __builtin_amdgcn_s_setprio(1);
        // ---- PV(it-1): independent of softmax(it) -> interleaves with the
        // exp/pf block below in one scheduling region.
        if (it > 0) {
            #pragma unroll
            for (int dt = 0; dt < 16; ++dt) {
                half8 vf = *(const half8*)(s_vP + (dt * 16 + l15) * 32 + vslot8);
                ctx[dt][0] = __builtin_amdgcn_mfma_f32_16x16x32_f16(vf, pfp[0], ctx[dt][0], 0, 0, 0);
                ctx[dt][1] = __builtin_amdgcn_mfma_f32_16x16x32_f16(vf, pfp[1], ctx[dt][1], 0, 0, 0);
            }
        }

        // ---- exp / pf(it) / l  (VALU; hides under PV MFMAs)
        half8 pfc[2];
        #pragma unroll
        for (int ct = 0; ct < 2; ++ct) {
            const float mm = m_c[ct];
            float rs = 0.f;
            #pragma unroll
            for (int r = 0; r < 4; ++r) {
                float p0 = __expf(S[0][ct][r] - mm);
                float p1 = __expf(S[1][ct][r] - mm);
                rs += p0 + p1;
                pfc[ct][r]     = (half_t)p0;
                pfc[ct][4 + r] = (half_t)p1;
            }
            rs += __shfl_xor(rs, 16);
            rs += __shfl_xor(rs, 32);
            l_c[ct] = l_c[ct] * (ct ? alpha1 : alpha0) + rs;
        }
        __builtin_amdgcn_s_setprio(0);

        // ---- rescale AFTER PV(it-1) accumulated (register data-dep on ctx)
        if (doresc) {
            #pragma unroll
            for (int dt = 0; dt < 16; ++dt)
                #pragma unroll
                for (int r = 0; r < 4; ++r) {
                    ctx[dt][0][r] *= alpha0;
                    ctx[dt][1][r] *= alpha1;
                }
        }

        pfp[0] = pfc[0];
        pfp[1] = pfc[1];

        if (pre) {
            __builtin_amdgcn_sched_barrier(0);   // pin PV reads+MFMAs above B2
            __builtin_amdgcn_s_barrier();        // B2: PV(it-1) reads done
            asm volatile("" ::: "memory");
            // vt(it+1) overwrites vt[(it-1)&1] -- safe after B2.
            const half_t* vt_ = vt_b + (size_t)(t0 + it + 1) * 8192;
            half_t* vdst = (half_t*)(smem + 32768 + (((it + 1) & 1) << 14));
            #pragma unroll
            for (int i = 0; i < 4; ++i) {
                const int sg = i * 4 + wv;
                dma16(vt_ + sg * 512 + lane * 8, vdst + sg * 512);
            }
        }
    }

    // drain everything (vt(NIT-1) still in flight) + global cert, then the
    // final deferred PV(NIT-1).
    asm volatile("s_waitcnt vmcnt(0)" ::: "memory");
    __builtin_amdgcn_s_barrier();
    asm volatile("" ::: "memory");
    {
        half_t* s_v = (half_t*)(smem + 32768 + (((NIT - 1) & 1) << 14));
        __builtin_amdgcn_s_setprio(1);
        #pragma unroll
        for (int dt = 0; dt < 16; ++dt) {
            half8 vf = *(const half8*)(s_v + (dt * 16 + l15) * 32 + vslot8);
            ctx[dt][0] = __builtin_amdgcn_mfma_f32_16x16x32_f16(vf, pfp[0], ctx[dt][0], 0, 0, 0);
            ctx[dt][1] = __builtin_amdgcn_mfma_f32_16x16x32_f16(vf, pfp[1], ctx[dt][1], 0, 0, 0);
        }
        __builtin_amdgcn_s_setprio(0);
    }

    // epilogue: normalized partial context (fp16) via per-wave LDS transpose.
    // scr regions (bytes < 34816) are per-wave private and don't overlap the
    // V1 buffer (>= 49152) read by the final PV -> no extra sync needed.
    float rinv[2] = {1.0f / l_c[0], 1.0f / l_c[1]};
    float* sw = scr + wv * (32 * 68);       // [q 32][stride 68] f32
    half_t* pcs = pc + (size_t)ks * NROWS * 256;
    #pragma unroll
    for (int rd = 0; rd < 4; ++rd) {
        #pragma unroll
        for (int dtl = 0; dtl < 4; ++dtl) {
            const int dt = rd * 4 + dtl;
            #pragma unroll
            for (int ct = 0; ct < 2; ++ct)
                #pragma unroll
                for (int r = 0; r < 4; ++r)
                    sw[(ct * 16 + l15) * 68 + dtl * 16 + quad * 4 + r] = ctx[dt][ct][r] * rinv[ct];
        }
        #pragma unroll
        for (int i = 0; i < 8; ++i) {
            int g = lane + i * 64;
            int q = g >> 4, dc = g & 15;
            float4_ v4 = *(const float4_*)(sw + q * 68 + dc * 4);
            half4v h4;
            #pragma unroll
            for (int j = 0; j < 4; ++j) h4[j] = (half_t)v4[j];
            *(half4v*)(pcs + (size_t)(qbase + q) * 256 + rd * 64 + dc * 4) = h4;
        }
    }
    if (quad == 0) {
        #pragma unroll
        for (int ct = 0; ct < 2; ++ct) {
            const size_t row = qbase + ct * 16 + l15;
            pm[(size_t)ks * NROWS + row] = m_c[ct];
            pl[(size_t)ks * NROWS + row] = l_c[ct];
        }
    }
}

// ---------------------------------------------------------------------------
// Kernel 4: merge the KS k-split partials.
// ---------------------------------------------------------------------------
__global__ __launch_bounds__(256) void combine_kernel(
    const half_t* __restrict__ pc, const float* __restrict__ pm,
    const float* __restrict__ pl, float* __restrict__ out)
{
    const int t = threadIdx.x;
    const int row = blockIdx.x * 4 + (t >> 6);
    const int d0 = (t & 63) * 4;
    float m[KS], l[KS];
    float ms = -1e30f;
    #pragma unroll
    for (int i = 0; i < KS; ++i) {
        m[i] = pm[(size_t)i * NROWS + row];
        l[i] = pl[(size_t)i * NROWS + row];
        ms = fmaxf(ms, m[i]);
    }
    float w[KS], tot = 0.f;
    #pragma unroll
    for (int i = 0; i < KS; ++i) {
        w[i] = l[i] * __expf(m[i] - ms);
        tot += w[i];
    }
    float inv = 1.0f / tot;
    float4_ o = {0.f, 0.f, 0.f, 0.f};
    #pragma unroll
    for (int i = 0; i < KS; ++i) {
        half4v y = *(const half4v*)(pc + ((size_t)i * NROWS + row) * 256 + d0);
        float wi = w[i] * inv;
        #pragma unroll
        for (int j = 0; j < 4; ++j) o[j] += wi * (float)y[j];
    }
    *(float4_*)(out + (size_t)row * 256 + d0) = o;
}

// ---------------------------------------------------------------------------
extern "C" void kernel_launch(void* const* d_in, const int* in_sizes, int n_in,
                              void* d_out, int out_size, void* d_ws, size_t ws_size,
                              hipStream_t stream) {
    const float* x      = (const float*)d_in[0];
    const float* states = (const float*)d_in[1];
    const float* Wq     = (const float*)d_in[2];
    const float* bq     = (const float*)d_in[3];
    const float* Wk     = (const float*)d_in[4];
    const float* bk     = (const float*)d_in[5];
    const float* Wv     = (const float*)d_in[6];
    const float* bv     = (const float*)d_in[7];
    const float* Wa     = (const float*)d_in[8];
    // ba (d_in[9]) contributes a per-row constant to scores -> softmax-invariant -> unused.
    float* out = (float*)d_out;

    char* ws = (char*)d_ws;
    size_t off = 0;
    auto alloc = [&](size_t bytes) -> void* {
        void* p = ws + off;
        off += (bytes + 255) & ~(size_t)255;
        return p;
    };
    half_t* M_hi  = (half_t*)alloc(65536 * 2);
    half_t* M_lo  = (half_t*)alloc(65536 * 2);
    half_t* Wk_hi = (half_t*)alloc(65536 * 2);
    half_t* Wk_lo = (half_t*)alloc(65536 * 2);
    half_t* Wv_hi = (half_t*)alloc(65536 * 2);
    float*  bq2   = (float*)alloc(256 * 4);
    half_t* q2_hi = (half_t*)alloc((size_t)NROWS * 256 * 2);
    half_t* k_hi  = (half_t*)alloc((size_t)NROWS * 256 * 2);   // tiled layout
    half_t* vT    = (half_t*)alloc((size_t)NROWS * 256 * 2);   // tiled layout
    half_t* pc    = (half_t*)alloc((size_t)KS * NROWS * 256 * 2);
    float*  pm    = (float*)alloc((size_t)KS * NROWS * 4);
    float*  pl    = (float*)alloc((size_t)KS * NROWS * 4);

    prep_kernel<<<256, 256, 0, stream>>>(Wq, Wk, Wv, Wa, bq,
                                         M_hi, M_lo, Wk_hi, Wk_lo, Wv_hi, bq2);
    linear_kernel<<<768, 256, 0, stream>>>(x, states,
                                           M_hi, M_lo, bq2,
                                           Wk_hi, Wk_lo, bk,
                                           Wv_hi, bv,
                                           q2_hi, k_hi, vT);
    attn_kernel<<<8 * 16 * KS, 256, 0, stream>>>(q2_hi, k_hi, vT,
                                                 pc, pm, pl);
    combine_kernel<<<NROWS / 4, 256, 0, stream>>>(pc, pm, pl, out);
}